// Round 7
// baseline (789.917 us; speedup 1.0000x reference)
//
#include <hip/hip_runtime.h>
#include <hip/hip_bf16.h>
#include <math.h>

#define B_SZ 4
#define CDIM 512
#define NPIX 4096
#define EPSN 1e-5f

typedef unsigned short u16;
typedef __attribute__((ext_vector_type(8))) short bf16x8;
typedef __attribute__((ext_vector_type(4))) float f32x4;

#define MFMA_BF16 __builtin_amdgcn_mfma_f32_16x16x32_bf16

static __device__ __forceinline__ float bf2f(u16 u) {
    return __uint_as_float(((unsigned)u) << 16);
}
static __device__ __forceinline__ u16 f2bf(float f) {
    unsigned u = __float_as_uint(f);
    unsigned r = (u + 0x7FFFu + ((u >> 16) & 1u)) >> 16;
    return (u16)r;
}

// ---------------------------------------------------------------------------
// zero_f32: rsb[n]=0
// ---------------------------------------------------------------------------
__global__ __launch_bounds__(256) void zero_f32(float* __restrict__ p, int n)
{
    int i = blockIdx.x * 256 + threadIdx.x;
    if (i < n) p[i] = 0.f;
}

// ---------------------------------------------------------------------------
// transpose_f2b: X fp32 [CDIM][NPIX] -> XT bf16 [NPIX][CDIM]. 64x64 tiles.
// ---------------------------------------------------------------------------
__global__ __launch_bounds__(256) void transpose_f2b(const float* __restrict__ X,
    u16* __restrict__ XT)
{
    __shared__ float T[64][65];
    const int t = threadIdx.x;
    const int n0 = blockIdx.x * 64, c0 = blockIdx.y * 64;
    #pragma unroll
    for (int p = 0; p < 4; p++) {
        int c_l = (t >> 4) + p * 16;
        int n_l = (t & 15) * 4;
        float4 v = *(const float4*)&X[(size_t)(c0 + c_l) * NPIX + n0 + n_l];
        T[c_l][n_l+0] = v.x; T[c_l][n_l+1] = v.y; T[c_l][n_l+2] = v.z; T[c_l][n_l+3] = v.w;
    }
    __syncthreads();
    #pragma unroll
    for (int p = 0; p < 4; p++) {
        int n_l = t >> 2;
        int cs  = (t & 3) * 4 + p * 16;
        ushort4 r;
        r.x = f2bf(T[cs+0][n_l]); r.y = f2bf(T[cs+1][n_l]);
        r.z = f2bf(T[cs+2][n_l]); r.w = f2bf(T[cs+3][n_l]);
        *(ushort4*)&XT[(size_t)(n0 + n_l) * CDIM + c0 + cs] = r;
    }
}

// ---------------------------------------------------------------------------
// conv64<TMODE>: D[o][n] = sum_c W[o][c] * XT[n][c]  (MFMA 16x16x32 bf16)
// 64x64 tile, 4 waves (2x2 of 32x32). TMODE: store D^T into Y=[n][o] (bf16).
// else: Y[o][n] = bf16(v), Y2[o][n] = bf16(v^2)   (v includes bias).
// ---------------------------------------------------------------------------
template<bool TMODE>
__global__ __launch_bounds__(256) void conv64(const u16* __restrict__ XT,
    const float* __restrict__ W, const float* __restrict__ bias,
    u16* __restrict__ Y, u16* __restrict__ Y2)
{
    const int t = threadIdx.x;
    const int lane = t & 63, wv = t >> 6;
    const int wr = wv >> 1, wc = wv & 1;
    const int n0 = blockIdx.x * 64;
    const int o0 = blockIdx.y * 64;
    const int g = lane >> 4, li = lane & 15;

    __shared__ short Aw[64][40];
    __shared__ short Bx[64][40];

    f32x4 acc[2][2] = {};
    const int srow = t >> 2, sseg = (t & 3) * 8;

    for (int kb = 0; kb < CDIM; kb += 32) {
        float4 w0 = *(const float4*)&W[(size_t)(o0 + srow) * CDIM + kb + sseg];
        float4 w1 = *(const float4*)&W[(size_t)(o0 + srow) * CDIM + kb + sseg + 4];
        bf16x8 bv = *(const bf16x8*)&XT[(size_t)(n0 + srow) * CDIM + kb + sseg];
        bf16x8 wa;
        wa[0] = (short)f2bf(w0.x); wa[1] = (short)f2bf(w0.y);
        wa[2] = (short)f2bf(w0.z); wa[3] = (short)f2bf(w0.w);
        wa[4] = (short)f2bf(w1.x); wa[5] = (short)f2bf(w1.y);
        wa[6] = (short)f2bf(w1.z); wa[7] = (short)f2bf(w1.w);
        __syncthreads();
        *(bf16x8*)&Aw[srow][sseg] = wa;
        *(bf16x8*)&Bx[srow][sseg] = bv;
        __syncthreads();
        bf16x8 a[2], b[2];
        #pragma unroll
        for (int i = 0; i < 2; i++) a[i] = *(const bf16x8*)&Aw[wr*32 + i*16 + li][g*8];
        #pragma unroll
        for (int j = 0; j < 2; j++) b[j] = *(const bf16x8*)&Bx[wc*32 + j*16 + li][g*8];
        #pragma unroll
        for (int i = 0; i < 2; i++)
            #pragma unroll
            for (int j = 0; j < 2; j++)
                acc[i][j] = MFMA_BF16(a[i], b[j], acc[i][j], 0, 0, 0);
    }

    #pragma unroll
    for (int i = 0; i < 2; i++) {
        const int orow = o0 + wr*32 + i*16 + 4*g;
        float4 bs = *(const float4*)&bias[orow];
        #pragma unroll
        for (int j = 0; j < 2; j++) {
            const int ncol = n0 + wc*32 + j*16 + li;
            if (TMODE) {
                ushort4 r;
                r.x = f2bf(acc[i][j][0] + bs.x);
                r.y = f2bf(acc[i][j][1] + bs.y);
                r.z = f2bf(acc[i][j][2] + bs.z);
                r.w = f2bf(acc[i][j][3] + bs.w);
                *(ushort4*)&Y[(size_t)ncol * CDIM + orow] = r;
            } else {
                const float bb[4] = { bs.x, bs.y, bs.z, bs.w };
                #pragma unroll
                for (int r = 0; r < 4; r++) {
                    float v = acc[i][j][r] + bb[r];
                    u16 hv = f2bf(v);
                    float hf = bf2f(hv);
                    Y [(size_t)(orow + r) * NPIX + ncol] = hv;
                    Y2[(size_t)(orow + r) * NPIX + ncol] = f2bf(hf * hf);
                }
            }
        }
    }
}

// ---------------------------------------------------------------------------
// col_norm_rows: FT [NPIX][CDIM] bf16 -> norm[n] = sqrt(sum_c FT[n][c]^2)
// ---------------------------------------------------------------------------
__global__ __launch_bounds__(256) void col_norm_rows(const u16* __restrict__ FT,
    float* __restrict__ norm)
{
    const int n = blockIdx.x * 256 + threadIdx.x;
    const u16* row = FT + (size_t)n * CDIM;
    float s = 0.f;
    for (int c = 0; c < CDIM; c += 8) {
        bf16x8 v = *(const bf16x8*)&row[c];
        #pragma unroll
        for (int e = 0; e < 8; e++) { float f = bf2f((u16)v[e]); s += f * f; }
    }
    norm[n] = sqrtf(s);
}

// ---------------------------------------------------------------------------
// s_gemm128: S[nl][m] = bf16(relu(dot(F_n,G_m)/((Fn+e)(Gn+e)) + 1))
// + row-sum epilogue: atomicAdd per output row of sum_m(bf16-rounded S).
// 128x128 tile, 4 waves (2x2 of 64x64), MFMA 16x16x32, K=CDIM.
// ---------------------------------------------------------------------------
__global__ __launch_bounds__(256) void s_gemm128(const u16* __restrict__ FT,
    const u16* __restrict__ GT, const float* __restrict__ Fn, const float* __restrict__ Gn,
    u16* __restrict__ S, float* __restrict__ rs, int strip_base)
{
    const int t = threadIdx.x;
    const int lane = t & 63, wv = t >> 6;
    const int wr = wv >> 1, wc = wv & 1;
    const int m0  = blockIdx.x * 128;
    const int nl0 = blockIdx.y * 128;
    const int ng0 = strip_base + nl0;
    const int g = lane >> 4, li = lane & 15;

    __shared__ short As[128][40];
    __shared__ short Bs[128][40];

    f32x4 acc[4][4] = {};
    const int srow = t >> 2, sseg = (t & 3) * 8;

    for (int kb = 0; kb < CDIM; kb += 32) {
        bf16x8 fa0 = *(const bf16x8*)&FT[(size_t)(ng0 + srow     ) * CDIM + kb + sseg];
        bf16x8 fa1 = *(const bf16x8*)&FT[(size_t)(ng0 + srow + 64) * CDIM + kb + sseg];
        bf16x8 gb0 = *(const bf16x8*)&GT[(size_t)(m0  + srow     ) * CDIM + kb + sseg];
        bf16x8 gb1 = *(const bf16x8*)&GT[(size_t)(m0  + srow + 64) * CDIM + kb + sseg];
        __syncthreads();
        *(bf16x8*)&As[srow     ][sseg] = fa0;
        *(bf16x8*)&As[srow + 64][sseg] = fa1;
        *(bf16x8*)&Bs[srow     ][sseg] = gb0;
        *(bf16x8*)&Bs[srow + 64][sseg] = gb1;
        __syncthreads();
        bf16x8 a[4], b[4];
        #pragma unroll
        for (int i = 0; i < 4; i++) a[i] = *(const bf16x8*)&As[wr*64 + i*16 + li][g*8];
        #pragma unroll
        for (int j = 0; j < 4; j++) b[j] = *(const bf16x8*)&Bs[wc*64 + j*16 + li][g*8];
        #pragma unroll
        for (int i = 0; i < 4; i++)
            #pragma unroll
            for (int j = 0; j < 4; j++)
                acc[i][j] = MFMA_BF16(a[i], b[j], acc[i][j], 0, 0, 0);
    }

    float gi[4];
    #pragma unroll
    for (int j = 0; j < 4; j++) gi[j] = 1.f / (Gn[m0 + wc*64 + j*16 + li] + EPSN);
    #pragma unroll
    for (int i = 0; i < 4; i++) {
        const int nl = nl0 + wr*64 + i*16 + 4*g;
        float4 fn4 = *(const float4*)&Fn[strip_base + nl];
        const float fi4[4] = { 1.f/(fn4.x + EPSN), 1.f/(fn4.y + EPSN),
                               1.f/(fn4.z + EPSN), 1.f/(fn4.w + EPSN) };
        float ps[4] = {0.f, 0.f, 0.f, 0.f};
        #pragma unroll
        for (int j = 0; j < 4; j++) {
            const int m = m0 + wc*64 + j*16 + li;
            #pragma unroll
            for (int r = 0; r < 4; r++) {
                float v = fmaxf(acc[i][j][r] * fi4[r] * gi[j] + 1.f, 0.f);
                u16 hv = f2bf(v);
                S[(size_t)(nl + r) * NPIX + m] = hv;
                ps[r] += bf2f(hv);           // sum the ROUNDED value (matches pv)
            }
        }
        #pragma unroll
        for (int r = 0; r < 4; r++) {
            float p = ps[r];
            p += __shfl_xor(p, 1);
            p += __shfl_xor(p, 2);
            p += __shfl_xor(p, 4);
            p += __shfl_xor(p, 8);
            if (li == 0) atomicAdd(&rs[strip_base + nl + r], p);
        }
    }
}

// ---------------------------------------------------------------------------
// pv64x128: mean/msq over k=m (dual MFMA chains), fused AdaIN epilogue.
// Tile 64c x 128n, 4 waves (2x2), each wave 32c x 64n. K=NPIX. out fp32.
// ---------------------------------------------------------------------------
__global__ __launch_bounds__(256) void pv64x128(const u16* __restrict__ Hb,
    const u16* __restrict__ H2b, const u16* __restrict__ Sb, const float* __restrict__ rs,
    const float* __restrict__ content_b, const float* __restrict__ mu,
    const float* __restrict__ isd, float* __restrict__ out_b, int strip_base)
{
    const int t = threadIdx.x;
    const int lane = t & 63, wv = t >> 6;
    const int wr = wv >> 1, wc = wv & 1;
    const int nl0 = blockIdx.x * 128;
    const int c0  = blockIdx.y * 64;
    const int g = lane >> 4, li = lane & 15;

    __shared__ short Ah[64][40];
    __shared__ short A2h[64][40];
    __shared__ short Ss[128][40];

    f32x4 am[2][4] = {};
    f32x4 aq[2][4] = {};
    const int arow = t >> 2, aseg = (t & 3) * 8;   // A loaders: 64 rows x 32 k
    const int srow = t >> 1, sseg = (t & 1) * 16;  // S loader: 128 rows x 32 k

    for (int kb = 0; kb < NPIX; kb += 32) {
        bf16x8 ha  = *(const bf16x8*)&Hb [(size_t)(c0  + arow) * NPIX + kb + aseg];
        bf16x8 h2a = *(const bf16x8*)&H2b[(size_t)(c0  + arow) * NPIX + kb + aseg];
        bf16x8 sa0 = *(const bf16x8*)&Sb [(size_t)(nl0 + srow) * NPIX + kb + sseg];
        bf16x8 sa1 = *(const bf16x8*)&Sb [(size_t)(nl0 + srow) * NPIX + kb + sseg + 8];
        __syncthreads();
        *(bf16x8*)&Ah [arow][aseg] = ha;
        *(bf16x8*)&A2h[arow][aseg] = h2a;
        *(bf16x8*)&Ss[srow][sseg]     = sa0;
        *(bf16x8*)&Ss[srow][sseg + 8] = sa1;
        __syncthreads();
        bf16x8 a[2], a2[2], b[4];
        #pragma unroll
        for (int i = 0; i < 2; i++) {
            a[i]  = *(const bf16x8*)&Ah [wr*32 + i*16 + li][g*8];
            a2[i] = *(const bf16x8*)&A2h[wr*32 + i*16 + li][g*8];
        }
        #pragma unroll
        for (int j = 0; j < 4; j++) b[j] = *(const bf16x8*)&Ss[wc*64 + j*16 + li][g*8];
        #pragma unroll
        for (int i = 0; i < 2; i++)
            #pragma unroll
            for (int j = 0; j < 4; j++) {
                am[i][j] = MFMA_BF16(a[i],  b[j], am[i][j], 0, 0, 0);
                aq[i][j] = MFMA_BF16(a2[i], b[j], aq[i][j], 0, 0, 0);
            }
    }

    float inv[4];
    #pragma unroll
    for (int j = 0; j < 4; j++)
        inv[j] = 1.f / (rs[strip_base + nl0 + wc*64 + j*16 + li] + EPSN);
    #pragma unroll
    for (int i = 0; i < 2; i++) {
        const int c = c0 + wr*32 + i*16 + 4*g;
        float4 mu4 = *(const float4*)&mu[c];
        float4 is4 = *(const float4*)&isd[c];
        const float muA[4] = { mu4.x, mu4.y, mu4.z, mu4.w };
        const float isA[4] = { is4.x, is4.y, is4.z, is4.w };
        #pragma unroll
        for (int j = 0; j < 4; j++) {
            const int n = strip_base + nl0 + wc*64 + j*16 + li;
            #pragma unroll
            for (int r = 0; r < 4; r++) {
                float mean = am[i][j][r] * inv[j];
                float msq  = aq[i][j][r] * inv[j];
                float sd   = sqrtf(fmaxf(msq - mean * mean, 0.f));
                float cv   = content_b[(size_t)(c + r) * NPIX + n];
                out_b[(size_t)(c + r) * NPIX + n] = sd * (cv - muA[r]) * isA[r] + mean;
            }
        }
    }
}

// ---------------------------------------------------------------------------
// content_stats: per (b,c) mean and 1/std (unbiased var, +1e-5), fp32 input
// ---------------------------------------------------------------------------
__global__ __launch_bounds__(256) void content_stats(const float* __restrict__ x,
    float* __restrict__ mu, float* __restrict__ isd)
{
    const int bc = blockIdx.x;
    const int tid = threadIdx.x;
    const float* row = x + (size_t)bc * NPIX;
    float s = 0.f, s2 = 0.f;
    for (int i = tid * 4; i < NPIX; i += 256 * 4) {
        float4 v = *(const float4*)&row[i];
        s  += v.x + v.y + v.z + v.w;
        s2 += v.x*v.x + v.y*v.y + v.z*v.z + v.w*v.w;
    }
    __shared__ float r1[256], r2[256];
    r1[tid] = s; r2[tid] = s2; __syncthreads();
    for (int st = 128; st; st >>= 1) {
        if (tid < st) { r1[tid] += r1[tid+st]; r2[tid] += r2[tid+st]; }
        __syncthreads();
    }
    if (tid == 0) {
        float m = r1[0] / NPIX;
        float var = (r2[0] - (float)NPIX * m * m) / (float)(NPIX - 1);
        mu[bc]  = m;
        isd[bc] = rsqrtf(var + 1e-5f);
    }
}

// ---------------------------------------------------------------------------
extern "C" void kernel_launch(void* const* d_in, const int* in_sizes, int n_in,
                              void* d_out, int out_size, void* d_ws, size_t ws_size,
                              hipStream_t stream)
{
    const float* content     = (const float*)d_in[0];
    const float* style       = (const float*)d_in[1];
    const float* content_key = (const float*)d_in[2];
    const float* style_key   = (const float*)d_in[3];
    const float* Wf  = (const float*)d_in[4];
    const float* bf_ = (const float*)d_in[5];
    const float* Wg  = (const float*)d_in[6];
    const float* bg  = (const float*)d_in[7];
    const float* Wh  = (const float*)d_in[8];
    const float* bh  = (const float*)d_in[9];
    float* out = (float*)d_out;

    const size_t TB = (size_t)CDIM * NPIX;   // elems per batch-tensor

    const size_t tail_bytes = ((size_t)NPIX * 3 + 2 * (size_t)B_SZ * CDIM) * 4 + 256;
    const size_t fixed = 4 * TB * 2 + tail_bytes;
    int ns = 512;   // min 512 so Sb (>=4MB) can host the XT transpose scratch
    for (int cand = NPIX; cand >= 512; cand >>= 1) {
        if (fixed + (size_t)NPIX * cand * 2 <= ws_size) { ns = cand; break; }
    }

    u16* FT  = (u16*)d_ws;                   // [NPIX][CDIM]
    u16* GT  = FT + TB;                      // [NPIX][CDIM]
    u16* Hb  = GT + TB;                      // [CDIM][NPIX]
    u16* H2b = Hb + TB;                      // [CDIM][NPIX]
    u16* Sb  = H2b + TB;                     // [ns][NPIX]
    u16* XT  = Sb;                           // transpose scratch (before S strips)
    float* Fn  = (float*)(Sb + (size_t)NPIX * ns);
    float* Gn  = Fn + NPIX;
    float* rsb = Gn + NPIX;
    float* mu  = rsb + NPIX;
    float* isd = mu + (size_t)B_SZ * CDIM;

    content_stats<<<B_SZ * CDIM, 256, 0, stream>>>(content, mu, isd);

    const dim3 gT(NPIX/64, CDIM/64);
    const dim3 gC(NPIX/64, CDIM/64);

    for (int b = 0; b < B_SZ; b++) {
        const size_t bo = (size_t)b * TB;

        transpose_f2b<<<gT, 256, 0, stream>>>(content_key + bo, XT);
        conv64<true><<<gC, 256, 0, stream>>>(XT, Wf, bf_, FT, nullptr);

        transpose_f2b<<<gT, 256, 0, stream>>>(style_key + bo, XT);
        conv64<true><<<gC, 256, 0, stream>>>(XT, Wg, bg, GT, nullptr);

        transpose_f2b<<<gT, 256, 0, stream>>>(style + bo, XT);
        conv64<false><<<gC, 256, 0, stream>>>(XT, Wh, bh, Hb, H2b);

        col_norm_rows<<<NPIX/256, 256, 0, stream>>>(FT, Fn);
        col_norm_rows<<<NPIX/256, 256, 0, stream>>>(GT, Gn);

        zero_f32<<<NPIX/256, 256, 0, stream>>>(rsb, NPIX);

        for (int s0 = 0; s0 < NPIX; s0 += ns) {
            s_gemm128<<<dim3(NPIX/128, ns/128), 256, 0, stream>>>(FT, GT, Fn, Gn, Sb, rsb, s0);
            pv64x128<<<dim3(ns/128, CDIM/64), 256, 0, stream>>>(Hb, H2b, Sb, rsb,
                    content + bo, mu + b*CDIM, isd + b*CDIM, out + bo, s0);
        }
    }
}

// Round 8
// 557.473 us; speedup vs baseline: 1.4170x; 1.4170x over previous
//
#include <hip/hip_runtime.h>
#include <hip/hip_bf16.h>
#include <math.h>

#define B_SZ 4
#define CDIM 512
#define NPIX 4096
#define EPSN 1e-5f

typedef unsigned short u16;
typedef __attribute__((ext_vector_type(8))) short bf16x8;
typedef __attribute__((ext_vector_type(4))) float f32x4;

#define MFMA_BF16 __builtin_amdgcn_mfma_f32_16x16x32_bf16

static __device__ __forceinline__ float bf2f(u16 u) {
    return __uint_as_float(((unsigned)u) << 16);
}
static __device__ __forceinline__ u16 f2bf(float f) {
    unsigned u = __float_as_uint(f);
    unsigned r = (u + 0x7FFFu + ((u >> 16) & 1u)) >> 16;
    return (u16)r;
}
// packed square of a bf16x8 fragment, truncating round (cheap, bias < 2^-8 rel)
static __device__ __forceinline__ bf16x8 sq_bf16x8(bf16x8 a) {
    union { bf16x8 v; unsigned w[4]; } in, out;
    in.v = a;
    #pragma unroll
    for (int k = 0; k < 4; k++) {
        unsigned wl = in.w[k] << 16;
        unsigned wh = in.w[k] & 0xFFFF0000u;
        float sl = __uint_as_float(wl); sl *= sl;
        float sh = __uint_as_float(wh); sh *= sh;
        out.w[k] = (__float_as_uint(sh) & 0xFFFF0000u) | (__float_as_uint(sl) >> 16);
    }
    return out.v;
}

// ---------------------------------------------------------------------------
// transpose3: z selects source fp32 [CDIM][NPIX] -> XTz bf16 [NPIX][CDIM]
// ---------------------------------------------------------------------------
__global__ __launch_bounds__(256) void transpose3(const float* __restrict__ X0,
    const float* __restrict__ X1, const float* __restrict__ X2,
    u16* __restrict__ T0, u16* __restrict__ T1, u16* __restrict__ T2, size_t boff)
{
    const int z = blockIdx.z;
    const float* X = (z == 0 ? X0 : z == 1 ? X1 : X2) + boff;
    u16* XT = z == 0 ? T0 : z == 1 ? T1 : T2;

    __shared__ float T[64][65];
    const int t = threadIdx.x;
    const int n0 = blockIdx.x * 64, c0 = blockIdx.y * 64;
    #pragma unroll
    for (int p = 0; p < 4; p++) {
        int c_l = (t >> 4) + p * 16;
        int n_l = (t & 15) * 4;
        float4 v = *(const float4*)&X[(size_t)(c0 + c_l) * NPIX + n0 + n_l];
        T[c_l][n_l+0] = v.x; T[c_l][n_l+1] = v.y; T[c_l][n_l+2] = v.z; T[c_l][n_l+3] = v.w;
    }
    __syncthreads();
    #pragma unroll
    for (int p = 0; p < 4; p++) {
        int n_l = t >> 2;
        int cs  = (t & 3) * 4 + p * 16;
        ushort4 r;
        r.x = f2bf(T[cs+0][n_l]); r.y = f2bf(T[cs+1][n_l]);
        r.z = f2bf(T[cs+2][n_l]); r.w = f2bf(T[cs+3][n_l]);
        *(ushort4*)&XT[(size_t)(n0 + n_l) * CDIM + c0 + cs] = r;
    }
}

// ---------------------------------------------------------------------------
// conv3: z in {0,1,2}: D[o][n] = bias[o] + sum_c Wz[o][c]*XTz[n][c]
// z<2: store D^T to Yz=[n][CDIM] bf16 (FT/GT). z==2: store Hb=[CDIM][NPIX].
// 64x64 tile, 4 waves (2x2 of 32x32). 2-phase prefetch pipeline.
// ---------------------------------------------------------------------------
__global__ __launch_bounds__(256) void conv3(
    const u16* __restrict__ XT0, const u16* __restrict__ XT1, const u16* __restrict__ XT2,
    const float* __restrict__ W0, const float* __restrict__ W1, const float* __restrict__ W2,
    const float* __restrict__ b0, const float* __restrict__ b1, const float* __restrict__ b2,
    u16* __restrict__ Y0, u16* __restrict__ Y1, u16* __restrict__ Y2)
{
    const int z = blockIdx.z;
    const u16* XT = z == 0 ? XT0 : z == 1 ? XT1 : XT2;
    const float* W = z == 0 ? W0 : z == 1 ? W1 : W2;
    const float* bias = z == 0 ? b0 : z == 1 ? b1 : b2;

    const int t = threadIdx.x;
    const int lane = t & 63, wv = t >> 6;
    const int wr = wv >> 1, wc = wv & 1;
    const int n0 = blockIdx.x * 64;
    const int o0 = blockIdx.y * 64;
    const int g = lane >> 4, li = lane & 15;

    __shared__ short Aw[64][40];
    __shared__ short Bx[64][40];

    f32x4 acc[2][2] = {};
    const int srow = t >> 2, sseg = (t & 3) * 8;

    float4 w0 = *(const float4*)&W[(size_t)(o0 + srow) * CDIM + sseg];
    float4 w1 = *(const float4*)&W[(size_t)(o0 + srow) * CDIM + sseg + 4];
    bf16x8 bv = *(const bf16x8*)&XT[(size_t)(n0 + srow) * CDIM + sseg];

    for (int kb = 0; kb < CDIM; kb += 32) {
        bf16x8 wa;
        wa[0] = (short)f2bf(w0.x); wa[1] = (short)f2bf(w0.y);
        wa[2] = (short)f2bf(w0.z); wa[3] = (short)f2bf(w0.w);
        wa[4] = (short)f2bf(w1.x); wa[5] = (short)f2bf(w1.y);
        wa[6] = (short)f2bf(w1.z); wa[7] = (short)f2bf(w1.w);
        __syncthreads();
        *(bf16x8*)&Aw[srow][sseg] = wa;
        *(bf16x8*)&Bx[srow][sseg] = bv;
        if (kb + 32 < CDIM) {
            w0 = *(const float4*)&W[(size_t)(o0 + srow) * CDIM + kb + 32 + sseg];
            w1 = *(const float4*)&W[(size_t)(o0 + srow) * CDIM + kb + 32 + sseg + 4];
            bv = *(const bf16x8*)&XT[(size_t)(n0 + srow) * CDIM + kb + 32 + sseg];
        }
        __syncthreads();
        bf16x8 a[2], b[2];
        #pragma unroll
        for (int i = 0; i < 2; i++) a[i] = *(const bf16x8*)&Aw[wr*32 + i*16 + li][g*8];
        #pragma unroll
        for (int j = 0; j < 2; j++) b[j] = *(const bf16x8*)&Bx[wc*32 + j*16 + li][g*8];
        #pragma unroll
        for (int i = 0; i < 2; i++)
            #pragma unroll
            for (int j = 0; j < 2; j++)
                acc[i][j] = MFMA_BF16(a[i], b[j], acc[i][j], 0, 0, 0);
    }

    #pragma unroll
    for (int i = 0; i < 2; i++) {
        const int orow = o0 + wr*32 + i*16 + 4*g;
        float4 bs = *(const float4*)&bias[orow];
        #pragma unroll
        for (int j = 0; j < 2; j++) {
            const int ncol = n0 + wc*32 + j*16 + li;
            if (z < 2) {
                u16* Y = z == 0 ? Y0 : Y1;
                ushort4 r;
                r.x = f2bf(acc[i][j][0] + bs.x);
                r.y = f2bf(acc[i][j][1] + bs.y);
                r.z = f2bf(acc[i][j][2] + bs.z);
                r.w = f2bf(acc[i][j][3] + bs.w);
                *(ushort4*)&Y[(size_t)ncol * CDIM + orow] = r;
            } else {
                const float bb[4] = { bs.x, bs.y, bs.z, bs.w };
                #pragma unroll
                for (int r = 0; r < 4; r++)
                    Y2[(size_t)(orow + r) * NPIX + ncol] = f2bf(acc[i][j][r] + bb[r]);
            }
        }
    }
}

// ---------------------------------------------------------------------------
// norm2: z=0: Fn[n]=sqrt(sum FT[n][c]^2), rs[n]=0 ; z=1: Gn from GT
// ---------------------------------------------------------------------------
__global__ __launch_bounds__(256) void norm2(const u16* __restrict__ FT,
    const u16* __restrict__ GT, float* __restrict__ Fn, float* __restrict__ Gn,
    float* __restrict__ rs)
{
    const int z = blockIdx.y;
    const int n = blockIdx.x * 256 + threadIdx.x;
    const u16* row = (z ? GT : FT) + (size_t)n * CDIM;
    float s = 0.f;
    for (int c = 0; c < CDIM; c += 8) {
        bf16x8 v = *(const bf16x8*)&row[c];
        #pragma unroll
        for (int e = 0; e < 8; e++) { float f = bf2f((u16)v[e]); s += f * f; }
    }
    (z ? Gn : Fn)[n] = sqrtf(s);
    if (!z) rs[n] = 0.f;
}

// ---------------------------------------------------------------------------
// s_gemm128: S[nl][m] = bf16(relu(dot/((Fn+e)(Gn+e)) + 1)), + rowsum atomics.
// 128x128 tile, 4 waves (2x2 of 64x64), K=CDIM, 2-phase prefetch.
// ---------------------------------------------------------------------------
__global__ __launch_bounds__(256) void s_gemm128(const u16* __restrict__ FT,
    const u16* __restrict__ GT, const float* __restrict__ Fn, const float* __restrict__ Gn,
    u16* __restrict__ S, float* __restrict__ rs, int strip_base)
{
    const int t = threadIdx.x;
    const int lane = t & 63, wv = t >> 6;
    const int wr = wv >> 1, wc = wv & 1;
    const int m0  = blockIdx.x * 128;
    const int nl0 = blockIdx.y * 128;
    const int ng0 = strip_base + nl0;
    const int g = lane >> 4, li = lane & 15;

    __shared__ short As[128][40];
    __shared__ short Bs[128][40];

    f32x4 acc[4][4] = {};
    const int srow = t >> 2, sseg = (t & 3) * 8;

    bf16x8 fa0 = *(const bf16x8*)&FT[(size_t)(ng0 + srow     ) * CDIM + sseg];
    bf16x8 fa1 = *(const bf16x8*)&FT[(size_t)(ng0 + srow + 64) * CDIM + sseg];
    bf16x8 gb0 = *(const bf16x8*)&GT[(size_t)(m0  + srow     ) * CDIM + sseg];
    bf16x8 gb1 = *(const bf16x8*)&GT[(size_t)(m0  + srow + 64) * CDIM + sseg];

    for (int kb = 0; kb < CDIM; kb += 32) {
        __syncthreads();
        *(bf16x8*)&As[srow     ][sseg] = fa0;
        *(bf16x8*)&As[srow + 64][sseg] = fa1;
        *(bf16x8*)&Bs[srow     ][sseg] = gb0;
        *(bf16x8*)&Bs[srow + 64][sseg] = gb1;
        if (kb + 32 < CDIM) {
            fa0 = *(const bf16x8*)&FT[(size_t)(ng0 + srow     ) * CDIM + kb + 32 + sseg];
            fa1 = *(const bf16x8*)&FT[(size_t)(ng0 + srow + 64) * CDIM + kb + 32 + sseg];
            gb0 = *(const bf16x8*)&GT[(size_t)(m0  + srow     ) * CDIM + kb + 32 + sseg];
            gb1 = *(const bf16x8*)&GT[(size_t)(m0  + srow + 64) * CDIM + kb + 32 + sseg];
        }
        __syncthreads();
        bf16x8 a[4], b[4];
        #pragma unroll
        for (int i = 0; i < 4; i++) a[i] = *(const bf16x8*)&As[wr*64 + i*16 + li][g*8];
        #pragma unroll
        for (int j = 0; j < 4; j++) b[j] = *(const bf16x8*)&Bs[wc*64 + j*16 + li][g*8];
        #pragma unroll
        for (int i = 0; i < 4; i++)
            #pragma unroll
            for (int j = 0; j < 4; j++)
                acc[i][j] = MFMA_BF16(a[i], b[j], acc[i][j], 0, 0, 0);
    }

    float gi[4];
    #pragma unroll
    for (int j = 0; j < 4; j++) gi[j] = 1.f / (Gn[m0 + wc*64 + j*16 + li] + EPSN);
    #pragma unroll
    for (int i = 0; i < 4; i++) {
        const int nl = nl0 + wr*64 + i*16 + 4*g;
        float4 fn4 = *(const float4*)&Fn[strip_base + nl];
        const float fi4[4] = { 1.f/(fn4.x + EPSN), 1.f/(fn4.y + EPSN),
                               1.f/(fn4.z + EPSN), 1.f/(fn4.w + EPSN) };
        float ps[4] = {0.f, 0.f, 0.f, 0.f};
        #pragma unroll
        for (int j = 0; j < 4; j++) {
            const int m = m0 + wc*64 + j*16 + li;
            #pragma unroll
            for (int r = 0; r < 4; r++) {
                float v = fmaxf(acc[i][j][r] * fi4[r] * gi[j] + 1.f, 0.f);
                u16 hv = f2bf(v);
                S[(size_t)(nl + r) * NPIX + m] = hv;
                ps[r] += bf2f(hv);
            }
        }
        #pragma unroll
        for (int r = 0; r < 4; r++) {
            float p = ps[r];
            p += __shfl_xor(p, 1);
            p += __shfl_xor(p, 2);
            p += __shfl_xor(p, 4);
            p += __shfl_xor(p, 8);
            if (li == 0) atomicAdd(&rs[strip_base + nl + r], p);
        }
    }
}

// ---------------------------------------------------------------------------
// pv64: mean/msq over k=m, H^2 computed in-register from H fragment.
// Tile 64c x 64n, 4 waves (2x2 of 32x32), K=NPIX, 2-phase prefetch. out fp32.
// ---------------------------------------------------------------------------
__global__ __launch_bounds__(256) void pv64(const u16* __restrict__ Hb,
    const u16* __restrict__ Sb, const float* __restrict__ rs,
    const float* __restrict__ content_b, const float* __restrict__ mu,
    const float* __restrict__ isd, float* __restrict__ out_b, int strip_base)
{
    const int t = threadIdx.x;
    const int lane = t & 63, wv = t >> 6;
    const int wr = wv >> 1, wc = wv & 1;
    const int nl0 = blockIdx.x * 64;
    const int c0  = blockIdx.y * 64;
    const int g = lane >> 4, li = lane & 15;

    __shared__ short Ah[64][40];
    __shared__ short Ss[64][40];

    f32x4 am[2][2] = {};
    f32x4 aq[2][2] = {};
    const int srow = t >> 2, sseg = (t & 3) * 8;

    bf16x8 ha = *(const bf16x8*)&Hb[(size_t)(c0  + srow) * NPIX + sseg];
    bf16x8 sa = *(const bf16x8*)&Sb[(size_t)(nl0 + srow) * NPIX + sseg];

    for (int kb = 0; kb < NPIX; kb += 32) {
        __syncthreads();
        *(bf16x8*)&Ah[srow][sseg] = ha;
        *(bf16x8*)&Ss[srow][sseg] = sa;
        if (kb + 32 < NPIX) {
            ha = *(const bf16x8*)&Hb[(size_t)(c0  + srow) * NPIX + kb + 32 + sseg];
            sa = *(const bf16x8*)&Sb[(size_t)(nl0 + srow) * NPIX + kb + 32 + sseg];
        }
        __syncthreads();
        bf16x8 a[2], a2[2], b[2];
        #pragma unroll
        for (int i = 0; i < 2; i++) {
            a[i]  = *(const bf16x8*)&Ah[wr*32 + i*16 + li][g*8];
            a2[i] = sq_bf16x8(a[i]);
        }
        #pragma unroll
        for (int j = 0; j < 2; j++) b[j] = *(const bf16x8*)&Ss[wc*32 + j*16 + li][g*8];
        #pragma unroll
        for (int i = 0; i < 2; i++)
            #pragma unroll
            for (int j = 0; j < 2; j++) {
                am[i][j] = MFMA_BF16(a[i],  b[j], am[i][j], 0, 0, 0);
                aq[i][j] = MFMA_BF16(a2[i], b[j], aq[i][j], 0, 0, 0);
            }
    }

    float inv[2];
    #pragma unroll
    for (int j = 0; j < 2; j++)
        inv[j] = 1.f / (rs[strip_base + nl0 + wc*32 + j*16 + li] + EPSN);
    #pragma unroll
    for (int i = 0; i < 2; i++) {
        const int c = c0 + wr*32 + i*16 + 4*g;
        float4 mu4 = *(const float4*)&mu[c];
        float4 is4 = *(const float4*)&isd[c];
        const float muA[4] = { mu4.x, mu4.y, mu4.z, mu4.w };
        const float isA[4] = { is4.x, is4.y, is4.z, is4.w };
        #pragma unroll
        for (int j = 0; j < 2; j++) {
            const int n = strip_base + nl0 + wc*32 + j*16 + li;
            #pragma unroll
            for (int r = 0; r < 4; r++) {
                float mean = am[i][j][r] * inv[j];
                float msq  = aq[i][j][r] * inv[j];
                float sd   = sqrtf(fmaxf(msq - mean * mean, 0.f));
                float cv   = content_b[(size_t)(c + r) * NPIX + n];
                out_b[(size_t)(c + r) * NPIX + n] = sd * (cv - muA[r]) * isA[r] + mean;
            }
        }
    }
}

// ---------------------------------------------------------------------------
// content_stats: per (b,c) mean and 1/std (unbiased var, +1e-5), fp32 input
// ---------------------------------------------------------------------------
__global__ __launch_bounds__(256) void content_stats(const float* __restrict__ x,
    float* __restrict__ mu, float* __restrict__ isd)
{
    const int bc = blockIdx.x;
    const int tid = threadIdx.x;
    const float* row = x + (size_t)bc * NPIX;
    float s = 0.f, s2 = 0.f;
    for (int i = tid * 4; i < NPIX; i += 256 * 4) {
        float4 v = *(const float4*)&row[i];
        s  += v.x + v.y + v.z + v.w;
        s2 += v.x*v.x + v.y*v.y + v.z*v.z + v.w*v.w;
    }
    __shared__ float r1[256], r2[256];
    r1[tid] = s; r2[tid] = s2; __syncthreads();
    for (int st = 128; st; st >>= 1) {
        if (tid < st) { r1[tid] += r1[tid+st]; r2[tid] += r2[tid+st]; }
        __syncthreads();
    }
    if (tid == 0) {
        float m = r1[0] / NPIX;
        float var = (r2[0] - (float)NPIX * m * m) / (float)(NPIX - 1);
        mu[bc]  = m;
        isd[bc] = rsqrtf(var + 1e-5f);
    }
}

// ---------------------------------------------------------------------------
extern "C" void kernel_launch(void* const* d_in, const int* in_sizes, int n_in,
                              void* d_out, int out_size, void* d_ws, size_t ws_size,
                              hipStream_t stream)
{
    const float* content     = (const float*)d_in[0];
    const float* style       = (const float*)d_in[1];
    const float* content_key = (const float*)d_in[2];
    const float* style_key   = (const float*)d_in[3];
    const float* Wf  = (const float*)d_in[4];
    const float* bf_ = (const float*)d_in[5];
    const float* Wg  = (const float*)d_in[6];
    const float* bg  = (const float*)d_in[7];
    const float* Wh  = (const float*)d_in[8];
    const float* bh  = (const float*)d_in[9];
    float* out = (float*)d_out;

    const size_t TB = (size_t)CDIM * NPIX;   // elems per batch-tensor

    // ws: FT, GT, Hb, XT0..2 (bf16, TB each) + Sb (bf16, NPIX*ns) + fp32 tail
    const size_t tail_bytes = ((size_t)NPIX * 3 + 2 * (size_t)B_SZ * CDIM) * 4 + 256;
    const size_t fixed = 6 * TB * 2 + tail_bytes;
    int ns = 512;
    for (int cand = NPIX; cand >= 512; cand >>= 1) {
        if (fixed + (size_t)NPIX * cand * 2 <= ws_size) { ns = cand; break; }
    }

    u16* FT  = (u16*)d_ws;                   // [NPIX][CDIM]
    u16* GT  = FT + TB;                      // [NPIX][CDIM]
    u16* Hb  = GT + TB;                      // [CDIM][NPIX]
    u16* XT0 = Hb + TB;                      // [NPIX][CDIM]
    u16* XT1 = XT0 + TB;
    u16* XT2 = XT1 + TB;
    u16* Sb  = XT2 + TB;                     // [ns][NPIX]
    float* Fn  = (float*)(Sb + (size_t)NPIX * ns);
    float* Gn  = Fn + NPIX;
    float* rsb = Gn + NPIX;
    float* mu  = rsb + NPIX;
    float* isd = mu + (size_t)B_SZ * CDIM;

    content_stats<<<B_SZ * CDIM, 256, 0, stream>>>(content, mu, isd);

    for (int b = 0; b < B_SZ; b++) {
        const size_t bo = (size_t)b * TB;

        transpose3<<<dim3(NPIX/64, CDIM/64, 3), 256, 0, stream>>>(
                content_key, style_key, style, XT0, XT1, XT2, bo);

        conv3<<<dim3(NPIX/64, CDIM/64, 3), 256, 0, stream>>>(
                XT0, XT1, XT2, Wf, Wg, Wh, bf_, bg, bh, FT, GT, Hb);

        norm2<<<dim3(NPIX/256, 2), 256, 0, stream>>>(FT, GT, Fn, Gn, rsb);

        for (int s0 = 0; s0 < NPIX; s0 += ns) {
            s_gemm128<<<dim3(NPIX/128, ns/128), 256, 0, stream>>>(FT, GT, Fn, Gn, Sb, rsb, s0);
            pv64<<<dim3(ns/64, CDIM/64), 256, 0, stream>>>(Hb, Sb, rsb,
                    content + bo, mu + b*CDIM, isd + b*CDIM, out + bo, s0);
        }
    }
}

// Round 9
// 550.433 us; speedup vs baseline: 1.4351x; 1.0128x over previous
//
#include <hip/hip_runtime.h>
#include <hip/hip_bf16.h>
#include <math.h>

#define B_SZ 4
#define CDIM 512
#define NPIX 4096
#define EPSN 1e-5f

typedef unsigned short u16;
typedef __attribute__((ext_vector_type(8))) short bf16x8;
typedef __attribute__((ext_vector_type(4))) float f32x4;

#define MFMA_BF16 __builtin_amdgcn_mfma_f32_16x16x32_bf16

static __device__ __forceinline__ float bf2f(u16 u) {
    return __uint_as_float(((unsigned)u) << 16);
}
static __device__ __forceinline__ u16 f2bf(float f) {
    unsigned u = __float_as_uint(f);
    unsigned r = (u + 0x7FFFu + ((u >> 16) & 1u)) >> 16;
    return (u16)r;
}
// packed square of a bf16x8 fragment, truncating round (bias < 2^-8 rel)
static __device__ __forceinline__ bf16x8 sq_bf16x8(bf16x8 a) {
    union { bf16x8 v; unsigned w[4]; } in, out;
    in.v = a;
    #pragma unroll
    for (int k = 0; k < 4; k++) {
        unsigned wl = in.w[k] << 16;
        unsigned wh = in.w[k] & 0xFFFF0000u;
        float sl = __uint_as_float(wl); sl *= sl;
        float sh = __uint_as_float(wh); sh *= sh;
        out.w[k] = (__float_as_uint(sh) & 0xFFFF0000u) | (__float_as_uint(sl) >> 16);
    }
    return out.v;
}

// ---------------------------------------------------------------------------
// transpose3: z selects source fp32 [CDIM][NPIX] -> XTz bf16 [NPIX][CDIM]
// ---------------------------------------------------------------------------
__global__ __launch_bounds__(256) void transpose3(const float* __restrict__ X0,
    const float* __restrict__ X1, const float* __restrict__ X2,
    u16* __restrict__ T0, u16* __restrict__ T1, u16* __restrict__ T2, size_t boff)
{
    const int z = blockIdx.z;
    const float* X = (z == 0 ? X0 : z == 1 ? X1 : X2) + boff;
    u16* XT = z == 0 ? T0 : z == 1 ? T1 : T2;

    __shared__ float T[64][65];
    const int t = threadIdx.x;
    const int n0 = blockIdx.x * 64, c0 = blockIdx.y * 64;
    #pragma unroll
    for (int p = 0; p < 4; p++) {
        int c_l = (t >> 4) + p * 16;
        int n_l = (t & 15) * 4;
        float4 v = *(const float4*)&X[(size_t)(c0 + c_l) * NPIX + n0 + n_l];
        T[c_l][n_l+0] = v.x; T[c_l][n_l+1] = v.y; T[c_l][n_l+2] = v.z; T[c_l][n_l+3] = v.w;
    }
    __syncthreads();
    #pragma unroll
    for (int p = 0; p < 4; p++) {
        int n_l = t >> 2;
        int cs  = (t & 3) * 4 + p * 16;
        ushort4 r;
        r.x = f2bf(T[cs+0][n_l]); r.y = f2bf(T[cs+1][n_l]);
        r.z = f2bf(T[cs+2][n_l]); r.w = f2bf(T[cs+3][n_l]);
        *(ushort4*)&XT[(size_t)(n0 + n_l) * CDIM + c0 + cs] = r;
    }
}

// ---------------------------------------------------------------------------
// conv3: z in {0,1,2}: D[o][n] = bias[o] + sum_c Wz[o][c]*XTz[n][c]
// z<2: store D^T to Yz=[n][CDIM] bf16 (FT/GT). z==2: store Hb=[CDIM][NPIX].
// 64x64 tile, 4 waves (2x2 of 32x32). 2-phase prefetch pipeline.
// ---------------------------------------------------------------------------
__global__ __launch_bounds__(256) void conv3(
    const u16* __restrict__ XT0, const u16* __restrict__ XT1, const u16* __restrict__ XT2,
    const float* __restrict__ W0, const float* __restrict__ W1, const float* __restrict__ W2,
    const float* __restrict__ b0, const float* __restrict__ b1, const float* __restrict__ b2,
    u16* __restrict__ Y0, u16* __restrict__ Y1, u16* __restrict__ Y2)
{
    const int z = blockIdx.z;
    const u16* XT = z == 0 ? XT0 : z == 1 ? XT1 : XT2;
    const float* W = z == 0 ? W0 : z == 1 ? W1 : W2;
    const float* bias = z == 0 ? b0 : z == 1 ? b1 : b2;

    const int t = threadIdx.x;
    const int lane = t & 63, wv = t >> 6;
    const int wr = wv >> 1, wc = wv & 1;
    const int n0 = blockIdx.x * 64;
    const int o0 = blockIdx.y * 64;
    const int g = lane >> 4, li = lane & 15;

    __shared__ short Aw[64][40];
    __shared__ short Bx[64][40];

    f32x4 acc[2][2] = {};
    const int srow = t >> 2, sseg = (t & 3) * 8;

    float4 w0 = *(const float4*)&W[(size_t)(o0 + srow) * CDIM + sseg];
    float4 w1 = *(const float4*)&W[(size_t)(o0 + srow) * CDIM + sseg + 4];
    bf16x8 bv = *(const bf16x8*)&XT[(size_t)(n0 + srow) * CDIM + sseg];

    for (int kb = 0; kb < CDIM; kb += 32) {
        bf16x8 wa;
        wa[0] = (short)f2bf(w0.x); wa[1] = (short)f2bf(w0.y);
        wa[2] = (short)f2bf(w0.z); wa[3] = (short)f2bf(w0.w);
        wa[4] = (short)f2bf(w1.x); wa[5] = (short)f2bf(w1.y);
        wa[6] = (short)f2bf(w1.z); wa[7] = (short)f2bf(w1.w);
        __syncthreads();
        *(bf16x8*)&Aw[srow][sseg] = wa;
        *(bf16x8*)&Bx[srow][sseg] = bv;
        if (kb + 32 < CDIM) {
            w0 = *(const float4*)&W[(size_t)(o0 + srow) * CDIM + kb + 32 + sseg];
            w1 = *(const float4*)&W[(size_t)(o0 + srow) * CDIM + kb + 32 + sseg + 4];
            bv = *(const bf16x8*)&XT[(size_t)(n0 + srow) * CDIM + kb + 32 + sseg];
        }
        __syncthreads();
        bf16x8 a[2], b[2];
        #pragma unroll
        for (int i = 0; i < 2; i++) a[i] = *(const bf16x8*)&Aw[wr*32 + i*16 + li][g*8];
        #pragma unroll
        for (int j = 0; j < 2; j++) b[j] = *(const bf16x8*)&Bx[wc*32 + j*16 + li][g*8];
        #pragma unroll
        for (int i = 0; i < 2; i++)
            #pragma unroll
            for (int j = 0; j < 2; j++)
                acc[i][j] = MFMA_BF16(a[i], b[j], acc[i][j], 0, 0, 0);
    }

    #pragma unroll
    for (int i = 0; i < 2; i++) {
        const int orow = o0 + wr*32 + i*16 + 4*g;
        float4 bs = *(const float4*)&bias[orow];
        #pragma unroll
        for (int j = 0; j < 2; j++) {
            const int ncol = n0 + wc*32 + j*16 + li;
            if (z < 2) {
                u16* Y = z == 0 ? Y0 : Y1;
                ushort4 r;
                r.x = f2bf(acc[i][j][0] + bs.x);
                r.y = f2bf(acc[i][j][1] + bs.y);
                r.z = f2bf(acc[i][j][2] + bs.z);
                r.w = f2bf(acc[i][j][3] + bs.w);
                *(ushort4*)&Y[(size_t)ncol * CDIM + orow] = r;
            } else {
                const float bb[4] = { bs.x, bs.y, bs.z, bs.w };
                #pragma unroll
                for (int r = 0; r < 4; r++)
                    Y2[(size_t)(orow + r) * NPIX + ncol] = f2bf(acc[i][j][r] + bb[r]);
            }
        }
    }
}

// ---------------------------------------------------------------------------
// norm2: z=0: Fn[n]=sqrt(sum FT[n][c]^2), rs[n]=0 ; z=1: Gn from GT
// ---------------------------------------------------------------------------
__global__ __launch_bounds__(256) void norm2(const u16* __restrict__ FT,
    const u16* __restrict__ GT, float* __restrict__ Fn, float* __restrict__ Gn,
    float* __restrict__ rs)
{
    const int z = blockIdx.y;
    const int n = blockIdx.x * 256 + threadIdx.x;
    const u16* row = (z ? GT : FT) + (size_t)n * CDIM;
    float s = 0.f;
    for (int c = 0; c < CDIM; c += 8) {
        bf16x8 v = *(const bf16x8*)&row[c];
        #pragma unroll
        for (int e = 0; e < 8; e++) { float f = bf2f((u16)v[e]); s += f * f; }
    }
    (z ? Gn : Fn)[n] = sqrtf(s);
    if (!z) rs[n] = 0.f;
}

// ---------------------------------------------------------------------------
// s_gemm128: S[nl][m] = bf16(relu(dot/((Fn+e)(Gn+e)) + 1)), + rowsum atomics.
// 128x128 tile, 4 waves (2x2 of 64x64), K=CDIM, 2-phase prefetch.
// Flat grid + XCD-locality swizzle (per-XCD: all m-tiles of one n-tile run
// consecutively -> GT L2-resident, FT slice shared).
// ---------------------------------------------------------------------------
__global__ __launch_bounds__(256) void s_gemm128(const u16* __restrict__ FT,
    const u16* __restrict__ GT, const float* __restrict__ Fn, const float* __restrict__ Gn,
    u16* __restrict__ S, float* __restrict__ rs, int strip_base, int swz)
{
    const int t = threadIdx.x;
    const int lane = t & 63, wv = t >> 6;
    const int wr = wv >> 1, wc = wv & 1;

    int mm, nn;
    if (swz) {            // (ns/128) % 8 == 0
        const int xk = blockIdx.x & 7, q = blockIdx.x >> 3;
        mm = q & 31;                      // NPIX/128 == 32
        nn = (q >> 5) * 8 + xk;
    } else {
        mm = blockIdx.x & 31;
        nn = blockIdx.x >> 5;
    }
    const int m0  = mm * 128;
    const int nl0 = nn * 128;
    const int ng0 = strip_base + nl0;
    const int g = lane >> 4, li = lane & 15;

    __shared__ short As[128][40];
    __shared__ short Bs[128][40];

    f32x4 acc[4][4] = {};
    const int srow = t >> 2, sseg = (t & 3) * 8;

    bf16x8 fa0 = *(const bf16x8*)&FT[(size_t)(ng0 + srow     ) * CDIM + sseg];
    bf16x8 fa1 = *(const bf16x8*)&FT[(size_t)(ng0 + srow + 64) * CDIM + sseg];
    bf16x8 gb0 = *(const bf16x8*)&GT[(size_t)(m0  + srow     ) * CDIM + sseg];
    bf16x8 gb1 = *(const bf16x8*)&GT[(size_t)(m0  + srow + 64) * CDIM + sseg];

    for (int kb = 0; kb < CDIM; kb += 32) {
        __syncthreads();
        *(bf16x8*)&As[srow     ][sseg] = fa0;
        *(bf16x8*)&As[srow + 64][sseg] = fa1;
        *(bf16x8*)&Bs[srow     ][sseg] = gb0;
        *(bf16x8*)&Bs[srow + 64][sseg] = gb1;
        if (kb + 32 < CDIM) {
            fa0 = *(const bf16x8*)&FT[(size_t)(ng0 + srow     ) * CDIM + kb + 32 + sseg];
            fa1 = *(const bf16x8*)&FT[(size_t)(ng0 + srow + 64) * CDIM + kb + 32 + sseg];
            gb0 = *(const bf16x8*)&GT[(size_t)(m0  + srow     ) * CDIM + kb + 32 + sseg];
            gb1 = *(const bf16x8*)&GT[(size_t)(m0  + srow + 64) * CDIM + kb + 32 + sseg];
        }
        __syncthreads();
        bf16x8 a[4], b[4];
        #pragma unroll
        for (int i = 0; i < 4; i++) a[i] = *(const bf16x8*)&As[wr*64 + i*16 + li][g*8];
        #pragma unroll
        for (int j = 0; j < 4; j++) b[j] = *(const bf16x8*)&Bs[wc*64 + j*16 + li][g*8];
        #pragma unroll
        for (int i = 0; i < 4; i++)
            #pragma unroll
            for (int j = 0; j < 4; j++)
                acc[i][j] = MFMA_BF16(a[i], b[j], acc[i][j], 0, 0, 0);
    }

    float gi[4];
    #pragma unroll
    for (int j = 0; j < 4; j++) gi[j] = 1.f / (Gn[m0 + wc*64 + j*16 + li] + EPSN);
    #pragma unroll
    for (int i = 0; i < 4; i++) {
        const int nl = nl0 + wr*64 + i*16 + 4*g;
        float4 fn4 = *(const float4*)&Fn[strip_base + nl];
        const float fi4[4] = { 1.f/(fn4.x + EPSN), 1.f/(fn4.y + EPSN),
                               1.f/(fn4.z + EPSN), 1.f/(fn4.w + EPSN) };
        float ps[4] = {0.f, 0.f, 0.f, 0.f};
        #pragma unroll
        for (int j = 0; j < 4; j++) {
            const int m = m0 + wc*64 + j*16 + li;
            #pragma unroll
            for (int r = 0; r < 4; r++) {
                float v = fmaxf(acc[i][j][r] * fi4[r] * gi[j] + 1.f, 0.f);
                u16 hv = f2bf(v);
                S[(size_t)(nl + r) * NPIX + m] = hv;
                ps[r] += bf2f(hv);
            }
        }
        #pragma unroll
        for (int r = 0; r < 4; r++) {
            float p = ps[r];
            p += __shfl_xor(p, 1);
            p += __shfl_xor(p, 2);
            p += __shfl_xor(p, 4);
            p += __shfl_xor(p, 8);
            if (li == 0) atomicAdd(&rs[strip_base + nl + r], p);
        }
    }
}

// ---------------------------------------------------------------------------
// pv64: mean/msq over k=m, H^2 in-register. 64c x 64n tile, 4 waves,
// K-step 64, 2-phase reg prefetch. Flat grid + XCD-locality swizzle:
// per XCD, 8 consecutive blocks = the 8 c-tiles of ONE n-tile (share the
// 64-row S slice in L2); successive groups re-read the same H rows (L2-res).
// ---------------------------------------------------------------------------
__global__ __launch_bounds__(256) void pv64(const u16* __restrict__ Hb,
    const u16* __restrict__ Sb, const float* __restrict__ rs,
    const float* __restrict__ content_b, const float* __restrict__ mu,
    const float* __restrict__ isd, float* __restrict__ out_b, int strip_base)
{
    const int t = threadIdx.x;
    const int lane = t & 63, wv = t >> 6;
    const int wr = wv >> 1, wc = wv & 1;

    const int xk = blockIdx.x & 7, q = blockIdx.x >> 3;
    const int c0  = (q & 7) * 64;          // CDIM/64 == 8
    const int nl0 = ((q >> 3) * 8 + xk) * 64;   // (ns/64) % 8 == 0 (ns >= 512)
    const int g = lane >> 4, li = lane & 15;

    __shared__ short Ah[64][72];
    __shared__ short Ss[64][72];

    f32x4 am[2][2] = {};
    f32x4 aq[2][2] = {};
    const int srow = t >> 2, sseg = (t & 3) * 8;
    const u16* Hrow = &Hb[(size_t)(c0  + srow) * NPIX];
    const u16* Srow = &Sb[(size_t)(nl0 + srow) * NPIX];

    bf16x8 ha0 = *(const bf16x8*)&Hrow[sseg];
    bf16x8 ha1 = *(const bf16x8*)&Hrow[sseg + 32];
    bf16x8 sa0 = *(const bf16x8*)&Srow[sseg];
    bf16x8 sa1 = *(const bf16x8*)&Srow[sseg + 32];

    for (int kb = 0; kb < NPIX; kb += 64) {
        __syncthreads();
        *(bf16x8*)&Ah[srow][sseg]      = ha0;
        *(bf16x8*)&Ah[srow][sseg + 32] = ha1;
        *(bf16x8*)&Ss[srow][sseg]      = sa0;
        *(bf16x8*)&Ss[srow][sseg + 32] = sa1;
        if (kb + 64 < NPIX) {
            ha0 = *(const bf16x8*)&Hrow[kb + 64 + sseg];
            ha1 = *(const bf16x8*)&Hrow[kb + 64 + sseg + 32];
            sa0 = *(const bf16x8*)&Srow[kb + 64 + sseg];
            sa1 = *(const bf16x8*)&Srow[kb + 64 + sseg + 32];
        }
        __syncthreads();
        #pragma unroll
        for (int ks = 0; ks < 2; ks++) {
            bf16x8 a[2], a2[2], b[2];
            #pragma unroll
            for (int i = 0; i < 2; i++) {
                a[i]  = *(const bf16x8*)&Ah[wr*32 + i*16 + li][ks*32 + g*8];
                a2[i] = sq_bf16x8(a[i]);
            }
            #pragma unroll
            for (int j = 0; j < 2; j++)
                b[j] = *(const bf16x8*)&Ss[wc*32 + j*16 + li][ks*32 + g*8];
            #pragma unroll
            for (int i = 0; i < 2; i++)
                #pragma unroll
                for (int j = 0; j < 2; j++) {
                    am[i][j] = MFMA_BF16(a[i],  b[j], am[i][j], 0, 0, 0);
                    aq[i][j] = MFMA_BF16(a2[i], b[j], aq[i][j], 0, 0, 0);
                }
        }
    }

    float inv[2];
    #pragma unroll
    for (int j = 0; j < 2; j++)
        inv[j] = 1.f / (rs[strip_base + nl0 + wc*32 + j*16 + li] + EPSN);
    #pragma unroll
    for (int i = 0; i < 2; i++) {
        const int c = c0 + wr*32 + i*16 + 4*g;
        float4 mu4 = *(const float4*)&mu[c];
        float4 is4 = *(const float4*)&isd[c];
        const float muA[4] = { mu4.x, mu4.y, mu4.z, mu4.w };
        const float isA[4] = { is4.x, is4.y, is4.z, is4.w };
        #pragma unroll
        for (int j = 0; j < 2; j++) {
            const int n = strip_base + nl0 + wc*32 + j*16 + li;
            #pragma unroll
            for (int r = 0; r < 4; r++) {
                float mean = am[i][j][r] * inv[j];
                float msq  = aq[i][j][r] * inv[j];
                float sd   = sqrtf(fmaxf(msq - mean * mean, 0.f));
                float cv   = content_b[(size_t)(c + r) * NPIX + n];
                out_b[(size_t)(c + r) * NPIX + n] = sd * (cv - muA[r]) * isA[r] + mean;
            }
        }
    }
}

// ---------------------------------------------------------------------------
// content_stats: per (b,c) mean and 1/std (unbiased var, +1e-5), fp32 input
// ---------------------------------------------------------------------------
__global__ __launch_bounds__(256) void content_stats(const float* __restrict__ x,
    float* __restrict__ mu, float* __restrict__ isd)
{
    const int bc = blockIdx.x;
    const int tid = threadIdx.x;
    const float* row = x + (size_t)bc * NPIX;
    float s = 0.f, s2 = 0.f;
    for (int i = tid * 4; i < NPIX; i += 256 * 4) {
        float4 v = *(const float4*)&row[i];
        s  += v.x + v.y + v.z + v.w;
        s2 += v.x*v.x + v.y*v.y + v.z*v.z + v.w*v.w;
    }
    __shared__ float r1[256], r2[256];
    r1[tid] = s; r2[tid] = s2; __syncthreads();
    for (int st = 128; st; st >>= 1) {
        if (tid < st) { r1[tid] += r1[tid+st]; r2[tid] += r2[tid+st]; }
        __syncthreads();
    }
    if (tid == 0) {
        float m = r1[0] / NPIX;
        float var = (r2[0] - (float)NPIX * m * m) / (float)(NPIX - 1);
        mu[bc]  = m;
        isd[bc] = rsqrtf(var + 1e-5f);
    }
}

// ---------------------------------------------------------------------------
extern "C" void kernel_launch(void* const* d_in, const int* in_sizes, int n_in,
                              void* d_out, int out_size, void* d_ws, size_t ws_size,
                              hipStream_t stream)
{
    const float* content     = (const float*)d_in[0];
    const float* style       = (const float*)d_in[1];
    const float* content_key = (const float*)d_in[2];
    const float* style_key   = (const float*)d_in[3];
    const float* Wf  = (const float*)d_in[4];
    const float* bf_ = (const float*)d_in[5];
    const float* Wg  = (const float*)d_in[6];
    const float* bg  = (const float*)d_in[7];
    const float* Wh  = (const float*)d_in[8];
    const float* bh  = (const float*)d_in[9];
    float* out = (float*)d_out;

    const size_t TB = (size_t)CDIM * NPIX;   // elems per batch-tensor

    const size_t tail_bytes = ((size_t)NPIX * 3 + 2 * (size_t)B_SZ * CDIM) * 4 + 256;
    const size_t fixed = 6 * TB * 2 + tail_bytes;
    int ns = 512;
    for (int cand = NPIX; cand >= 512; cand >>= 1) {
        if (fixed + (size_t)NPIX * cand * 2 <= ws_size) { ns = cand; break; }
    }

    u16* FT  = (u16*)d_ws;                   // [NPIX][CDIM]
    u16* GT  = FT + TB;                      // [NPIX][CDIM]
    u16* Hb  = GT + TB;                      // [CDIM][NPIX]
    u16* XT0 = Hb + TB;                      // [NPIX][CDIM]
    u16* XT1 = XT0 + TB;
    u16* XT2 = XT1 + TB;
    u16* Sb  = XT2 + TB;                     // [ns][NPIX]
    float* Fn  = (float*)(Sb + (size_t)NPIX * ns);
    float* Gn  = Fn + NPIX;
    float* rsb = Gn + NPIX;
    float* mu  = rsb + NPIX;
    float* isd = mu + (size_t)B_SZ * CDIM;

    content_stats<<<B_SZ * CDIM, 256, 0, stream>>>(content, mu, isd);

    const int sg_swz = ((ns / 128) % 8 == 0) ? 1 : 0;
    const int sg_blocks = (NPIX / 128) * (ns / 128);
    const int pv_blocks = 8 * (ns / 64);

    for (int b = 0; b < B_SZ; b++) {
        const size_t bo = (size_t)b * TB;

        transpose3<<<dim3(NPIX/64, CDIM/64, 3), 256, 0, stream>>>(
                content_key, style_key, style, XT0, XT1, XT2, bo);

        conv3<<<dim3(NPIX/64, CDIM/64, 3), 256, 0, stream>>>(
                XT0, XT1, XT2, Wf, Wg, Wh, bf_, bg, bh, FT, GT, Hb);

        norm2<<<dim3(NPIX/256, 2), 256, 0, stream>>>(FT, GT, Fn, Gn, rsb);

        for (int s0 = 0; s0 < NPIX; s0 += ns) {
            s_gemm128<<<sg_blocks, 256, 0, stream>>>(FT, GT, Fn, Gn, Sb, rsb, s0, sg_swz);
            pv64<<<pv_blocks, 256, 0, stream>>>(Hb, Sb, rsb,
                    content + bo, mu + b*CDIM, isd + b*CDIM, out + bo, s0);
        }
    }
}

// Round 10
// 540.748 us; speedup vs baseline: 1.4608x; 1.0179x over previous
//
#include <hip/hip_runtime.h>
#include <hip/hip_bf16.h>
#include <math.h>

#define B_SZ 4
#define CDIM 512
#define NPIX 4096
#define EPSN 1e-5f

typedef unsigned short u16;
typedef __attribute__((ext_vector_type(8))) short bf16x8;
typedef __attribute__((ext_vector_type(4))) float f32x4;
typedef __attribute__((ext_vector_type(16))) float f32x16;

#define MFMA_BF16 __builtin_amdgcn_mfma_f32_16x16x32_bf16
#define MFMA32    __builtin_amdgcn_mfma_f32_32x32x16_bf16

static __device__ __forceinline__ float bf2f(u16 u) {
    return __uint_as_float(((unsigned)u) << 16);
}
static __device__ __forceinline__ u16 f2bf(float f) {
    unsigned u = __float_as_uint(f);
    unsigned r = (u + 0x7FFFu + ((u >> 16) & 1u)) >> 16;
    return (u16)r;
}
// packed square of a bf16x8 fragment, truncating round (bias < 2^-8 rel)
static __device__ __forceinline__ bf16x8 sq_bf16x8(bf16x8 a) {
    union { bf16x8 v; unsigned w[4]; } in, out;
    in.v = a;
    #pragma unroll
    for (int k = 0; k < 4; k++) {
        unsigned wl = in.w[k] << 16;
        unsigned wh = in.w[k] & 0xFFFF0000u;
        float sl = __uint_as_float(wl); sl *= sl;
        float sh = __uint_as_float(wh); sh *= sh;
        out.w[k] = (__float_as_uint(sh) & 0xFFFF0000u) | (__float_as_uint(sl) >> 16);
    }
    return out.v;
}

// ---------------------------------------------------------------------------
// transpose3: z selects source fp32 [CDIM][NPIX] -> XTz bf16 [NPIX][CDIM]
// ---------------------------------------------------------------------------
__global__ __launch_bounds__(256) void transpose3(const float* __restrict__ X0,
    const float* __restrict__ X1, const float* __restrict__ X2,
    u16* __restrict__ T0, u16* __restrict__ T1, u16* __restrict__ T2, size_t boff)
{
    const int z = blockIdx.z;
    const float* X = (z == 0 ? X0 : z == 1 ? X1 : X2) + boff;
    u16* XT = z == 0 ? T0 : z == 1 ? T1 : T2;

    __shared__ float T[64][65];
    const int t = threadIdx.x;
    const int n0 = blockIdx.x * 64, c0 = blockIdx.y * 64;
    #pragma unroll
    for (int p = 0; p < 4; p++) {
        int c_l = (t >> 4) + p * 16;
        int n_l = (t & 15) * 4;
        float4 v = *(const float4*)&X[(size_t)(c0 + c_l) * NPIX + n0 + n_l];
        T[c_l][n_l+0] = v.x; T[c_l][n_l+1] = v.y; T[c_l][n_l+2] = v.z; T[c_l][n_l+3] = v.w;
    }
    __syncthreads();
    #pragma unroll
    for (int p = 0; p < 4; p++) {
        int n_l = t >> 2;
        int cs  = (t & 3) * 4 + p * 16;
        ushort4 r;
        r.x = f2bf(T[cs+0][n_l]); r.y = f2bf(T[cs+1][n_l]);
        r.z = f2bf(T[cs+2][n_l]); r.w = f2bf(T[cs+3][n_l]);
        *(ushort4*)&XT[(size_t)(n0 + n_l) * CDIM + c0 + cs] = r;
    }
}

// ---------------------------------------------------------------------------
// conv3: z in {0,1,2}: D[o][n] = bias[o] + sum_c Wz[o][c]*XTz[n][c]
// z<2: store D^T to Yz=[n][CDIM] bf16 (FT/GT). z==2: store Hb=[CDIM][NPIX].
// 64x64 tile, 4 waves (2x2 of 32x32). 2-phase prefetch pipeline.
// ---------------------------------------------------------------------------
__global__ __launch_bounds__(256) void conv3(
    const u16* __restrict__ XT0, const u16* __restrict__ XT1, const u16* __restrict__ XT2,
    const float* __restrict__ W0, const float* __restrict__ W1, const float* __restrict__ W2,
    const float* __restrict__ b0, const float* __restrict__ b1, const float* __restrict__ b2,
    u16* __restrict__ Y0, u16* __restrict__ Y1, u16* __restrict__ Y2)
{
    const int z = blockIdx.z;
    const u16* XT = z == 0 ? XT0 : z == 1 ? XT1 : XT2;
    const float* W = z == 0 ? W0 : z == 1 ? W1 : W2;
    const float* bias = z == 0 ? b0 : z == 1 ? b1 : b2;

    const int t = threadIdx.x;
    const int lane = t & 63, wv = t >> 6;
    const int wr = wv >> 1, wc = wv & 1;
    const int n0 = blockIdx.x * 64;
    const int o0 = blockIdx.y * 64;
    const int g = lane >> 4, li = lane & 15;

    __shared__ short Aw[64][40];
    __shared__ short Bx[64][40];

    f32x4 acc[2][2] = {};
    const int srow = t >> 2, sseg = (t & 3) * 8;

    float4 w0 = *(const float4*)&W[(size_t)(o0 + srow) * CDIM + sseg];
    float4 w1 = *(const float4*)&W[(size_t)(o0 + srow) * CDIM + sseg + 4];
    bf16x8 bv = *(const bf16x8*)&XT[(size_t)(n0 + srow) * CDIM + sseg];

    for (int kb = 0; kb < CDIM; kb += 32) {
        bf16x8 wa;
        wa[0] = (short)f2bf(w0.x); wa[1] = (short)f2bf(w0.y);
        wa[2] = (short)f2bf(w0.z); wa[3] = (short)f2bf(w0.w);
        wa[4] = (short)f2bf(w1.x); wa[5] = (short)f2bf(w1.y);
        wa[6] = (short)f2bf(w1.z); wa[7] = (short)f2bf(w1.w);
        __syncthreads();
        *(bf16x8*)&Aw[srow][sseg] = wa;
        *(bf16x8*)&Bx[srow][sseg] = bv;
        if (kb + 32 < CDIM) {
            w0 = *(const float4*)&W[(size_t)(o0 + srow) * CDIM + kb + 32 + sseg];
            w1 = *(const float4*)&W[(size_t)(o0 + srow) * CDIM + kb + 32 + sseg + 4];
            bv = *(const bf16x8*)&XT[(size_t)(n0 + srow) * CDIM + kb + 32 + sseg];
        }
        __syncthreads();
        bf16x8 a[2], b[2];
        #pragma unroll
        for (int i = 0; i < 2; i++) a[i] = *(const bf16x8*)&Aw[wr*32 + i*16 + li][g*8];
        #pragma unroll
        for (int j = 0; j < 2; j++) b[j] = *(const bf16x8*)&Bx[wc*32 + j*16 + li][g*8];
        #pragma unroll
        for (int i = 0; i < 2; i++)
            #pragma unroll
            for (int j = 0; j < 2; j++)
                acc[i][j] = MFMA_BF16(a[i], b[j], acc[i][j], 0, 0, 0);
    }

    #pragma unroll
    for (int i = 0; i < 2; i++) {
        const int orow = o0 + wr*32 + i*16 + 4*g;
        float4 bs = *(const float4*)&bias[orow];
        #pragma unroll
        for (int j = 0; j < 2; j++) {
            const int ncol = n0 + wc*32 + j*16 + li;
            if (z < 2) {
                u16* Y = z == 0 ? Y0 : Y1;
                ushort4 r;
                r.x = f2bf(acc[i][j][0] + bs.x);
                r.y = f2bf(acc[i][j][1] + bs.y);
                r.z = f2bf(acc[i][j][2] + bs.z);
                r.w = f2bf(acc[i][j][3] + bs.w);
                *(ushort4*)&Y[(size_t)ncol * CDIM + orow] = r;
            } else {
                const float bb[4] = { bs.x, bs.y, bs.z, bs.w };
                #pragma unroll
                for (int r = 0; r < 4; r++)
                    Y2[(size_t)(orow + r) * NPIX + ncol] = f2bf(acc[i][j][r] + bb[r]);
            }
        }
    }
}

// ---------------------------------------------------------------------------
// norm2: z=0: Fn[n]=sqrt(sum FT[n][c]^2), rs[n]=0 ; z=1: Gn from GT
// ---------------------------------------------------------------------------
__global__ __launch_bounds__(256) void norm2(const u16* __restrict__ FT,
    const u16* __restrict__ GT, float* __restrict__ Fn, float* __restrict__ Gn,
    float* __restrict__ rs)
{
    const int z = blockIdx.y;
    const int n = blockIdx.x * 256 + threadIdx.x;
    const u16* row = (z ? GT : FT) + (size_t)n * CDIM;
    float s = 0.f;
    for (int c = 0; c < CDIM; c += 8) {
        bf16x8 v = *(const bf16x8*)&row[c];
        #pragma unroll
        for (int e = 0; e < 8; e++) { float f = bf2f((u16)v[e]); s += f * f; }
    }
    (z ? Gn : Fn)[n] = sqrtf(s);
    if (!z) rs[n] = 0.f;
}

// ---------------------------------------------------------------------------
// s_gemm128: S[nl][m] = bf16(relu(dot/((Fn+e)(Gn+e)) + 1)), + rowsum atomics.
// 128x128 tile, 4 waves (2x2 of 64x64), K=CDIM, 2-phase prefetch.
// ---------------------------------------------------------------------------
__global__ __launch_bounds__(256) void s_gemm128(const u16* __restrict__ FT,
    const u16* __restrict__ GT, const float* __restrict__ Fn, const float* __restrict__ Gn,
    u16* __restrict__ S, float* __restrict__ rs, int strip_base, int swz)
{
    const int t = threadIdx.x;
    const int lane = t & 63, wv = t >> 6;
    const int wr = wv >> 1, wc = wv & 1;

    int mm, nn;
    if (swz) {            // (ns/128) % 8 == 0
        const int xk = blockIdx.x & 7, q = blockIdx.x >> 3;
        mm = q & 31;                      // NPIX/128 == 32
        nn = (q >> 5) * 8 + xk;
    } else {
        mm = blockIdx.x & 31;
        nn = blockIdx.x >> 5;
    }
    const int m0  = mm * 128;
    const int nl0 = nn * 128;
    const int ng0 = strip_base + nl0;
    const int g = lane >> 4, li = lane & 15;

    __shared__ short As[128][40];
    __shared__ short Bs[128][40];

    f32x4 acc[4][4] = {};
    const int srow = t >> 2, sseg = (t & 3) * 8;

    bf16x8 fa0 = *(const bf16x8*)&FT[(size_t)(ng0 + srow     ) * CDIM + sseg];
    bf16x8 fa1 = *(const bf16x8*)&FT[(size_t)(ng0 + srow + 64) * CDIM + sseg];
    bf16x8 gb0 = *(const bf16x8*)&GT[(size_t)(m0  + srow     ) * CDIM + sseg];
    bf16x8 gb1 = *(const bf16x8*)&GT[(size_t)(m0  + srow + 64) * CDIM + sseg];

    for (int kb = 0; kb < CDIM; kb += 32) {
        __syncthreads();
        *(bf16x8*)&As[srow     ][sseg] = fa0;
        *(bf16x8*)&As[srow + 64][sseg] = fa1;
        *(bf16x8*)&Bs[srow     ][sseg] = gb0;
        *(bf16x8*)&Bs[srow + 64][sseg] = gb1;
        if (kb + 32 < CDIM) {
            fa0 = *(const bf16x8*)&FT[(size_t)(ng0 + srow     ) * CDIM + kb + 32 + sseg];
            fa1 = *(const bf16x8*)&FT[(size_t)(ng0 + srow + 64) * CDIM + kb + 32 + sseg];
            gb0 = *(const bf16x8*)&GT[(size_t)(m0  + srow     ) * CDIM + kb + 32 + sseg];
            gb1 = *(const bf16x8*)&GT[(size_t)(m0  + srow + 64) * CDIM + kb + 32 + sseg];
        }
        __syncthreads();
        bf16x8 a[4], b[4];
        #pragma unroll
        for (int i = 0; i < 4; i++) a[i] = *(const bf16x8*)&As[wr*64 + i*16 + li][g*8];
        #pragma unroll
        for (int j = 0; j < 4; j++) b[j] = *(const bf16x8*)&Bs[wc*64 + j*16 + li][g*8];
        #pragma unroll
        for (int i = 0; i < 4; i++)
            #pragma unroll
            for (int j = 0; j < 4; j++)
                acc[i][j] = MFMA_BF16(a[i], b[j], acc[i][j], 0, 0, 0);
    }

    float gi[4];
    #pragma unroll
    for (int j = 0; j < 4; j++) gi[j] = 1.f / (Gn[m0 + wc*64 + j*16 + li] + EPSN);
    #pragma unroll
    for (int i = 0; i < 4; i++) {
        const int nl = nl0 + wr*64 + i*16 + 4*g;
        float4 fn4 = *(const float4*)&Fn[strip_base + nl];
        const float fi4[4] = { 1.f/(fn4.x + EPSN), 1.f/(fn4.y + EPSN),
                               1.f/(fn4.z + EPSN), 1.f/(fn4.w + EPSN) };
        float ps[4] = {0.f, 0.f, 0.f, 0.f};
        #pragma unroll
        for (int j = 0; j < 4; j++) {
            const int m = m0 + wc*64 + j*16 + li;
            #pragma unroll
            for (int r = 0; r < 4; r++) {
                float v = fmaxf(acc[i][j][r] * fi4[r] * gi[j] + 1.f, 0.f);
                u16 hv = f2bf(v);
                S[(size_t)(nl + r) * NPIX + m] = hv;
                ps[r] += bf2f(hv);
            }
        }
        #pragma unroll
        for (int r = 0; r < 4; r++) {
            float p = ps[r];
            p += __shfl_xor(p, 1);
            p += __shfl_xor(p, 2);
            p += __shfl_xor(p, 4);
            p += __shfl_xor(p, 8);
            if (li == 0) atomicAdd(&rs[strip_base + nl + r], p);
        }
    }
}

// ---------------------------------------------------------------------------
// pv64: mean/msq over k=m via MFMA 32x32x16 (dual chains, H^2 in-register).
// 64c x 64n tile, 4 waves (2x2 of 32x32 each). K-step 64, 2-phase prefetch.
// Combined XOR-swizzled LDS [64 rows][256 B]: A-half (H k0..63) | S-half.
// slot(16B) ^= (row&15) on BOTH write and read -> bank-conflict-free floor.
// Flat grid + XCD-locality swizzle (8 c-tiles of one n-tile per XCD group).
// ---------------------------------------------------------------------------
__global__ __launch_bounds__(256) void pv64(const u16* __restrict__ Hb,
    const u16* __restrict__ Sb, const float* __restrict__ rs,
    const float* __restrict__ content_b, const float* __restrict__ mu,
    const float* __restrict__ isd, float* __restrict__ out_b, int strip_base)
{
    const int t = threadIdx.x;
    const int lane = t & 63, wv = t >> 6;
    const int wr = wv >> 1, wc = wv & 1;
    const int l31 = lane & 31, h = lane >> 5;

    const int xk = blockIdx.x & 7, q = blockIdx.x >> 3;
    const int c0  = (q & 7) * 64;               // CDIM/64 == 8
    const int nl0 = ((q >> 3) * 8 + xk) * 64;   // (ns/64) % 8 == 0

    __shared__ short AS[64][128];               // 64 rows x 256 B, swizzled

    f32x16 am = {}, aq = {};
    const int srow  = t >> 2;
    const int sbyte = (t & 3) * 16;             // 0,16,32,48
    const u16* Hrow = &Hb[(size_t)(c0  + srow) * NPIX];
    const u16* Srow = &Sb[(size_t)(nl0 + srow) * NPIX];
    const int sw = (srow & 15) << 4;
    short* wp = &AS[srow][0];
    const int wA0 = ((sbyte      ) ^ sw) >> 1;  // short offsets, 16B-granular
    const int wA1 = ((sbyte +  64) ^ sw) >> 1;
    const int wS0 = ((sbyte + 128) ^ sw) >> 1;
    const int wS1 = ((sbyte + 192) ^ sw) >> 1;

    bf16x8 ha0 = *(const bf16x8*)&Hrow[sbyte/2];
    bf16x8 ha1 = *(const bf16x8*)&Hrow[sbyte/2 + 32];
    bf16x8 sa0 = *(const bf16x8*)&Srow[sbyte/2];
    bf16x8 sa1 = *(const bf16x8*)&Srow[sbyte/2 + 32];

    const int ra = wr*32 + l31, rb = wc*32 + l31;
    const short* rpa = &AS[ra][0];
    const short* rpb = &AS[rb][0];
    const int swa = (ra & 15) << 4, swb = (rb & 15) << 4;

    for (int kb = 0; kb < NPIX; kb += 64) {
        __syncthreads();
        *(bf16x8*)&wp[wA0] = ha0;
        *(bf16x8*)&wp[wA1] = ha1;
        *(bf16x8*)&wp[wS0] = sa0;
        *(bf16x8*)&wp[wS1] = sa1;
        if (kb + 64 < NPIX) {
            ha0 = *(const bf16x8*)&Hrow[kb + 64 + sbyte/2];
            ha1 = *(const bf16x8*)&Hrow[kb + 64 + sbyte/2 + 32];
            sa0 = *(const bf16x8*)&Srow[kb + 64 + sbyte/2];
            sa1 = *(const bf16x8*)&Srow[kb + 64 + sbyte/2 + 32];
        }
        __syncthreads();
        #pragma unroll
        for (int ks = 0; ks < 4; ks++) {
            bf16x8 a  = *(const bf16x8*)&rpa[((ks*32 + h*16      ) ^ swa) >> 1];
            bf16x8 b  = *(const bf16x8*)&rpb[((ks*32 + h*16 + 128) ^ swb) >> 1];
            bf16x8 a2 = sq_bf16x8(a);
            am = MFMA32(a,  b, am, 0, 0, 0);
            aq = MFMA32(a2, b, aq, 0, 0, 0);
        }
    }

    // C layout (32x32): col = lane&31 (n), row = (reg&3) + 8*(reg>>2) + 4*h (c)
    const int n = strip_base + nl0 + wc*32 + l31;
    const float inv = 1.f / (rs[n] + EPSN);
    #pragma unroll
    for (int qd = 0; qd < 4; qd++) {
        const int cb = c0 + wr*32 + 8*qd + 4*h;
        float4 mu4 = *(const float4*)&mu[cb];
        float4 is4 = *(const float4*)&isd[cb];
        const float muA[4] = { mu4.x, mu4.y, mu4.z, mu4.w };
        const float isA[4] = { is4.x, is4.y, is4.z, is4.w };
        #pragma unroll
        for (int r2 = 0; r2 < 4; r2++) {
            const int reg = qd*4 + r2;
            float mean = am[reg] * inv;
            float msq  = aq[reg] * inv;
            float sd   = sqrtf(fmaxf(msq - mean*mean, 0.f));
            float cv   = content_b[(size_t)(cb + r2) * NPIX + n];
            out_b[(size_t)(cb + r2) * NPIX + n] = sd * (cv - muA[r2]) * isA[r2] + mean;
        }
    }
}

// ---------------------------------------------------------------------------
// content_stats: per (b,c) mean and 1/std (unbiased var, +1e-5), fp32 input
// ---------------------------------------------------------------------------
__global__ __launch_bounds__(256) void content_stats(const float* __restrict__ x,
    float* __restrict__ mu, float* __restrict__ isd)
{
    const int bc = blockIdx.x;
    const int tid = threadIdx.x;
    const float* row = x + (size_t)bc * NPIX;
    float s = 0.f, s2 = 0.f;
    for (int i = tid * 4; i < NPIX; i += 256 * 4) {
        float4 v = *(const float4*)&row[i];
        s  += v.x + v.y + v.z + v.w;
        s2 += v.x*v.x + v.y*v.y + v.z*v.z + v.w*v.w;
    }
    __shared__ float r1[256], r2[256];
    r1[tid] = s; r2[tid] = s2; __syncthreads();
    for (int st = 128; st; st >>= 1) {
        if (tid < st) { r1[tid] += r1[tid+st]; r2[tid] += r2[tid+st]; }
        __syncthreads();
    }
    if (tid == 0) {
        float m = r1[0] / NPIX;
        float var = (r2[0] - (float)NPIX * m * m) / (float)(NPIX - 1);
        mu[bc]  = m;
        isd[bc] = rsqrtf(var + 1e-5f);
    }
}

// ---------------------------------------------------------------------------
extern "C" void kernel_launch(void* const* d_in, const int* in_sizes, int n_in,
                              void* d_out, int out_size, void* d_ws, size_t ws_size,
                              hipStream_t stream)
{
    const float* content     = (const float*)d_in[0];
    const float* style       = (const float*)d_in[1];
    const float* content_key = (const float*)d_in[2];
    const float* style_key   = (const float*)d_in[3];
    const float* Wf  = (const float*)d_in[4];
    const float* bf_ = (const float*)d_in[5];
    const float* Wg  = (const float*)d_in[6];
    const float* bg  = (const float*)d_in[7];
    const float* Wh  = (const float*)d_in[8];
    const float* bh  = (const float*)d_in[9];
    float* out = (float*)d_out;

    const size_t TB = (size_t)CDIM * NPIX;   // elems per batch-tensor

    const size_t tail_bytes = ((size_t)NPIX * 3 + 2 * (size_t)B_SZ * CDIM) * 4 + 256;
    const size_t fixed = 6 * TB * 2 + tail_bytes;
    int ns = 512;
    for (int cand = NPIX; cand >= 512; cand >>= 1) {
        if (fixed + (size_t)NPIX * cand * 2 <= ws_size) { ns = cand; break; }
    }

    u16* FT  = (u16*)d_ws;                   // [NPIX][CDIM]
    u16* GT  = FT + TB;                      // [NPIX][CDIM]
    u16* Hb  = GT + TB;                      // [CDIM][NPIX]
    u16* XT0 = Hb + TB;                      // [NPIX][CDIM]
    u16* XT1 = XT0 + TB;
    u16* XT2 = XT1 + TB;
    u16* Sb  = XT2 + TB;                     // [ns][NPIX]
    float* Fn  = (float*)(Sb + (size_t)NPIX * ns);
    float* Gn  = Fn + NPIX;
    float* rsb = Gn + NPIX;
    float* mu  = rsb + NPIX;
    float* isd = mu + (size_t)B_SZ * CDIM;

    content_stats<<<B_SZ * CDIM, 256, 0, stream>>>(content, mu, isd);

    const int sg_swz = ((ns / 128) % 8 == 0) ? 1 : 0;
    const int sg_blocks = (NPIX / 128) * (ns / 128);
    const int pv_blocks = 8 * (ns / 64);

    for (int b = 0; b < B_SZ; b++) {
        const size_t bo = (size_t)b * TB;

        transpose3<<<dim3(NPIX/64, CDIM/64, 3), 256, 0, stream>>>(
                content_key, style_key, style, XT0, XT1, XT2, bo);

        conv3<<<dim3(NPIX/64, CDIM/64, 3), 256, 0, stream>>>(
                XT0, XT1, XT2, Wf, Wg, Wh, bf_, bg, bh, FT, GT, Hb);

        norm2<<<dim3(NPIX/256, 2), 256, 0, stream>>>(FT, GT, Fn, Gn, rsb);

        for (int s0 = 0; s0 < NPIX; s0 += ns) {
            s_gemm128<<<sg_blocks, 256, 0, stream>>>(FT, GT, Fn, Gn, Sb, rsb, s0, sg_swz);
            pv64<<<pv_blocks, 256, 0, stream>>>(Hb, Sb, rsb,
                    content + bo, mu + b*CDIM, isd + b*CDIM, out + bo, s0);
        }
    }
}

// Round 11
// 534.158 us; speedup vs baseline: 1.4788x; 1.0123x over previous
//
#include <hip/hip_runtime.h>
#include <hip/hip_bf16.h>
#include <math.h>

#define B_SZ 4
#define CDIM 512
#define NPIX 4096
#define EPSN 1e-5f

typedef unsigned short u16;
typedef __attribute__((ext_vector_type(8))) short bf16x8;
typedef __attribute__((ext_vector_type(4))) float f32x4;
typedef __attribute__((ext_vector_type(16))) float f32x16;

#define MFMA_BF16 __builtin_amdgcn_mfma_f32_16x16x32_bf16
#define MFMA32    __builtin_amdgcn_mfma_f32_32x32x16_bf16

static __device__ __forceinline__ float bf2f(u16 u) {
    return __uint_as_float(((unsigned)u) << 16);
}
static __device__ __forceinline__ u16 f2bf(float f) {
    unsigned u = __float_as_uint(f);
    unsigned r = (u + 0x7FFFu + ((u >> 16) & 1u)) >> 16;
    return (u16)r;
}
// packed square of a bf16x8 fragment, truncating round (bias < 2^-8 rel)
static __device__ __forceinline__ bf16x8 sq_bf16x8(bf16x8 a) {
    union { bf16x8 v; unsigned w[4]; } in, out;
    in.v = a;
    #pragma unroll
    for (int k = 0; k < 4; k++) {
        unsigned wl = in.w[k] << 16;
        unsigned wh = in.w[k] & 0xFFFF0000u;
        float sl = __uint_as_float(wl); sl *= sl;
        float sh = __uint_as_float(wh); sh *= sh;
        out.w[k] = (__float_as_uint(sh) & 0xFFFF0000u) | (__float_as_uint(sl) >> 16);
    }
    return out.v;
}

// ---------------------------------------------------------------------------
// transpose3: z selects source fp32 [CDIM][NPIX] -> XTz bf16 [NPIX][CDIM]
// ---------------------------------------------------------------------------
__global__ __launch_bounds__(256) void transpose3(const float* __restrict__ X0,
    const float* __restrict__ X1, const float* __restrict__ X2,
    u16* __restrict__ T0, u16* __restrict__ T1, u16* __restrict__ T2, size_t boff)
{
    const int z = blockIdx.z;
    const float* X = (z == 0 ? X0 : z == 1 ? X1 : X2) + boff;
    u16* XT = z == 0 ? T0 : z == 1 ? T1 : T2;

    __shared__ float T[64][65];
    const int t = threadIdx.x;
    const int n0 = blockIdx.x * 64, c0 = blockIdx.y * 64;
    #pragma unroll
    for (int p = 0; p < 4; p++) {
        int c_l = (t >> 4) + p * 16;
        int n_l = (t & 15) * 4;
        float4 v = *(const float4*)&X[(size_t)(c0 + c_l) * NPIX + n0 + n_l];
        T[c_l][n_l+0] = v.x; T[c_l][n_l+1] = v.y; T[c_l][n_l+2] = v.z; T[c_l][n_l+3] = v.w;
    }
    __syncthreads();
    #pragma unroll
    for (int p = 0; p < 4; p++) {
        int n_l = t >> 2;
        int cs  = (t & 3) * 4 + p * 16;
        ushort4 r;
        r.x = f2bf(T[cs+0][n_l]); r.y = f2bf(T[cs+1][n_l]);
        r.z = f2bf(T[cs+2][n_l]); r.w = f2bf(T[cs+3][n_l]);
        *(ushort4*)&XT[(size_t)(n0 + n_l) * CDIM + c0 + cs] = r;
    }
}

// ---------------------------------------------------------------------------
// conv3: z in {0,1,2}: D[o][n] = bias[o] + sum_c Wz[o][c]*XTz[n][c]
// z<2: store D^T to Yz=[n][CDIM] bf16 (FT/GT). z==2: store Hb=[CDIM][NPIX].
// 64x64 tile, 4 waves (2x2 of 32x32). 2-phase prefetch pipeline.
// ---------------------------------------------------------------------------
__global__ __launch_bounds__(256) void conv3(
    const u16* __restrict__ XT0, const u16* __restrict__ XT1, const u16* __restrict__ XT2,
    const float* __restrict__ W0, const float* __restrict__ W1, const float* __restrict__ W2,
    const float* __restrict__ b0, const float* __restrict__ b1, const float* __restrict__ b2,
    u16* __restrict__ Y0, u16* __restrict__ Y1, u16* __restrict__ Y2)
{
    const int z = blockIdx.z;
    const u16* XT = z == 0 ? XT0 : z == 1 ? XT1 : XT2;
    const float* W = z == 0 ? W0 : z == 1 ? W1 : W2;
    const float* bias = z == 0 ? b0 : z == 1 ? b1 : b2;

    const int t = threadIdx.x;
    const int lane = t & 63, wv = t >> 6;
    const int wr = wv >> 1, wc = wv & 1;
    const int n0 = blockIdx.x * 64;
    const int o0 = blockIdx.y * 64;
    const int g = lane >> 4, li = lane & 15;

    __shared__ short Aw[64][40];
    __shared__ short Bx[64][40];

    f32x4 acc[2][2] = {};
    const int srow = t >> 2, sseg = (t & 3) * 8;

    float4 w0 = *(const float4*)&W[(size_t)(o0 + srow) * CDIM + sseg];
    float4 w1 = *(const float4*)&W[(size_t)(o0 + srow) * CDIM + sseg + 4];
    bf16x8 bv = *(const bf16x8*)&XT[(size_t)(n0 + srow) * CDIM + sseg];

    for (int kb = 0; kb < CDIM; kb += 32) {
        bf16x8 wa;
        wa[0] = (short)f2bf(w0.x); wa[1] = (short)f2bf(w0.y);
        wa[2] = (short)f2bf(w0.z); wa[3] = (short)f2bf(w0.w);
        wa[4] = (short)f2bf(w1.x); wa[5] = (short)f2bf(w1.y);
        wa[6] = (short)f2bf(w1.z); wa[7] = (short)f2bf(w1.w);
        __syncthreads();
        *(bf16x8*)&Aw[srow][sseg] = wa;
        *(bf16x8*)&Bx[srow][sseg] = bv;
        if (kb + 32 < CDIM) {
            w0 = *(const float4*)&W[(size_t)(o0 + srow) * CDIM + kb + 32 + sseg];
            w1 = *(const float4*)&W[(size_t)(o0 + srow) * CDIM + kb + 32 + sseg + 4];
            bv = *(const bf16x8*)&XT[(size_t)(n0 + srow) * CDIM + kb + 32 + sseg];
        }
        __syncthreads();
        bf16x8 a[2], b[2];
        #pragma unroll
        for (int i = 0; i < 2; i++) a[i] = *(const bf16x8*)&Aw[wr*32 + i*16 + li][g*8];
        #pragma unroll
        for (int j = 0; j < 2; j++) b[j] = *(const bf16x8*)&Bx[wc*32 + j*16 + li][g*8];
        #pragma unroll
        for (int i = 0; i < 2; i++)
            #pragma unroll
            for (int j = 0; j < 2; j++)
                acc[i][j] = MFMA_BF16(a[i], b[j], acc[i][j], 0, 0, 0);
    }

    #pragma unroll
    for (int i = 0; i < 2; i++) {
        const int orow = o0 + wr*32 + i*16 + 4*g;
        float4 bs = *(const float4*)&bias[orow];
        #pragma unroll
        for (int j = 0; j < 2; j++) {
            const int ncol = n0 + wc*32 + j*16 + li;
            if (z < 2) {
                u16* Y = z == 0 ? Y0 : Y1;
                ushort4 r;
                r.x = f2bf(acc[i][j][0] + bs.x);
                r.y = f2bf(acc[i][j][1] + bs.y);
                r.z = f2bf(acc[i][j][2] + bs.z);
                r.w = f2bf(acc[i][j][3] + bs.w);
                *(ushort4*)&Y[(size_t)ncol * CDIM + orow] = r;
            } else {
                const float bb[4] = { bs.x, bs.y, bs.z, bs.w };
                #pragma unroll
                for (int r = 0; r < 4; r++)
                    Y2[(size_t)(orow + r) * NPIX + ncol] = f2bf(acc[i][j][r] + bb[r]);
            }
        }
    }
}

// ---------------------------------------------------------------------------
// norm2: z=0: Fn[n]=sqrt(sum FT[n][c]^2), rs[n]=0 ; z=1: Gn from GT
// ---------------------------------------------------------------------------
__global__ __launch_bounds__(256) void norm2(const u16* __restrict__ FT,
    const u16* __restrict__ GT, float* __restrict__ Fn, float* __restrict__ Gn,
    float* __restrict__ rs)
{
    const int z = blockIdx.y;
    const int n = blockIdx.x * 256 + threadIdx.x;
    const u16* row = (z ? GT : FT) + (size_t)n * CDIM;
    float s = 0.f;
    for (int c = 0; c < CDIM; c += 8) {
        bf16x8 v = *(const bf16x8*)&row[c];
        #pragma unroll
        for (int e = 0; e < 8; e++) { float f = bf2f((u16)v[e]); s += f * f; }
    }
    (z ? Gn : Fn)[n] = sqrtf(s);
    if (!z) rs[n] = 0.f;
}

// ---------------------------------------------------------------------------
// s_gemm128: S[nl][m] = bf16(relu(dot/((Fn+e)(Gn+e)) + 1)), + rowsum atomics.
// 128x128 tile, 4 waves (2x2 of 64x64), K=CDIM.
// LDS double-buffer + 2-slot register prefetch (issue-early / write-late):
// phase i: issue loads tile i+2 -> slot(i&1); compute tile i from LDS[i&1];
// ds_write tile i+1 (slot (i+1)&1) into LDS[(i+1)&1]; ONE barrier.
// ---------------------------------------------------------------------------
__global__ __launch_bounds__(256) void s_gemm128(const u16* __restrict__ FT,
    const u16* __restrict__ GT, const float* __restrict__ Fn, const float* __restrict__ Gn,
    u16* __restrict__ S, float* __restrict__ rs, int strip_base, int swz)
{
    const int t = threadIdx.x;
    const int lane = t & 63, wv = t >> 6;
    const int wr = wv >> 1, wc = wv & 1;

    int mm, nn;
    if (swz) {            // (ns/128) % 8 == 0
        const int xk = blockIdx.x & 7, q = blockIdx.x >> 3;
        mm = q & 31;                      // NPIX/128 == 32
        nn = (q >> 5) * 8 + xk;
    } else {
        mm = blockIdx.x & 31;
        nn = blockIdx.x >> 5;
    }
    const int m0  = mm * 128;
    const int nl0 = nn * 128;
    const int ng0 = strip_base + nl0;
    const int g = lane >> 4, li = lane & 15;

    __shared__ short As[2][128][40];
    __shared__ short Bs[2][128][40];

    f32x4 acc[4][4] = {};
    const int srow = t >> 2, sseg = (t & 3) * 8;
    const u16* Fr0 = &FT[(size_t)(ng0 + srow     ) * CDIM];
    const u16* Fr1 = &FT[(size_t)(ng0 + srow + 64) * CDIM];
    const u16* Gr0 = &GT[(size_t)(m0  + srow     ) * CDIM];
    const u16* Gr1 = &GT[(size_t)(m0  + srow + 64) * CDIM];

    // prologue: slotA <- tile0, slotB <- tile1; LDS[0] <- slotA
    bf16x8 fA0 = *(const bf16x8*)&Fr0[sseg];
    bf16x8 fA1 = *(const bf16x8*)&Fr1[sseg];
    bf16x8 gA0 = *(const bf16x8*)&Gr0[sseg];
    bf16x8 gA1 = *(const bf16x8*)&Gr1[sseg];
    bf16x8 fB0 = *(const bf16x8*)&Fr0[32 + sseg];
    bf16x8 fB1 = *(const bf16x8*)&Fr1[32 + sseg];
    bf16x8 gB0 = *(const bf16x8*)&Gr0[32 + sseg];
    bf16x8 gB1 = *(const bf16x8*)&Gr1[32 + sseg];
    *(bf16x8*)&As[0][srow     ][sseg] = fA0;
    *(bf16x8*)&As[0][srow + 64][sseg] = fA1;
    *(bf16x8*)&Bs[0][srow     ][sseg] = gA0;
    *(bf16x8*)&Bs[0][srow + 64][sseg] = gA1;
    __syncthreads();

    for (int kb = 0; kb < CDIM; kb += 64) {
        // phase even: compute tile kb/32 from [0]
        if (kb + 64 < CDIM) {
            fA0 = *(const bf16x8*)&Fr0[kb + 64 + sseg];
            fA1 = *(const bf16x8*)&Fr1[kb + 64 + sseg];
            gA0 = *(const bf16x8*)&Gr0[kb + 64 + sseg];
            gA1 = *(const bf16x8*)&Gr1[kb + 64 + sseg];
        }
        {
            bf16x8 a[4], b[4];
            #pragma unroll
            for (int i = 0; i < 4; i++) a[i] = *(const bf16x8*)&As[0][wr*64 + i*16 + li][g*8];
            #pragma unroll
            for (int j = 0; j < 4; j++) b[j] = *(const bf16x8*)&Bs[0][wc*64 + j*16 + li][g*8];
            #pragma unroll
            for (int i = 0; i < 4; i++)
                #pragma unroll
                for (int j = 0; j < 4; j++)
                    acc[i][j] = MFMA_BF16(a[i], b[j], acc[i][j], 0, 0, 0);
        }
        *(bf16x8*)&As[1][srow     ][sseg] = fB0;
        *(bf16x8*)&As[1][srow + 64][sseg] = fB1;
        *(bf16x8*)&Bs[1][srow     ][sseg] = gB0;
        *(bf16x8*)&Bs[1][srow + 64][sseg] = gB1;
        __syncthreads();
        // phase odd: compute tile kb/32+1 from [1]
        if (kb + 96 < CDIM) {
            fB0 = *(const bf16x8*)&Fr0[kb + 96 + sseg];
            fB1 = *(const bf16x8*)&Fr1[kb + 96 + sseg];
            gB0 = *(const bf16x8*)&Gr0[kb + 96 + sseg];
            gB1 = *(const bf16x8*)&Gr1[kb + 96 + sseg];
        }
        {
            bf16x8 a[4], b[4];
            #pragma unroll
            for (int i = 0; i < 4; i++) a[i] = *(const bf16x8*)&As[1][wr*64 + i*16 + li][g*8];
            #pragma unroll
            for (int j = 0; j < 4; j++) b[j] = *(const bf16x8*)&Bs[1][wc*64 + j*16 + li][g*8];
            #pragma unroll
            for (int i = 0; i < 4; i++)
                #pragma unroll
                for (int j = 0; j < 4; j++)
                    acc[i][j] = MFMA_BF16(a[i], b[j], acc[i][j], 0, 0, 0);
        }
        if (kb + 64 < CDIM) {
            *(bf16x8*)&As[0][srow     ][sseg] = fA0;
            *(bf16x8*)&As[0][srow + 64][sseg] = fA1;
            *(bf16x8*)&Bs[0][srow     ][sseg] = gA0;
            *(bf16x8*)&Bs[0][srow + 64][sseg] = gA1;
        }
        __syncthreads();
    }

    float gi[4];
    #pragma unroll
    for (int j = 0; j < 4; j++) gi[j] = 1.f / (Gn[m0 + wc*64 + j*16 + li] + EPSN);
    #pragma unroll
    for (int i = 0; i < 4; i++) {
        const int nl = nl0 + wr*64 + i*16 + 4*g;
        float4 fn4 = *(const float4*)&Fn[strip_base + nl];
        const float fi4[4] = { 1.f/(fn4.x + EPSN), 1.f/(fn4.y + EPSN),
                               1.f/(fn4.z + EPSN), 1.f/(fn4.w + EPSN) };
        float ps[4] = {0.f, 0.f, 0.f, 0.f};
        #pragma unroll
        for (int j = 0; j < 4; j++) {
            const int m = m0 + wc*64 + j*16 + li;
            #pragma unroll
            for (int r = 0; r < 4; r++) {
                float v = fmaxf(acc[i][j][r] * fi4[r] * gi[j] + 1.f, 0.f);
                u16 hv = f2bf(v);
                S[(size_t)(nl + r) * NPIX + m] = hv;
                ps[r] += bf2f(hv);
            }
        }
        #pragma unroll
        for (int r = 0; r < 4; r++) {
            float p = ps[r];
            p += __shfl_xor(p, 1);
            p += __shfl_xor(p, 2);
            p += __shfl_xor(p, 4);
            p += __shfl_xor(p, 8);
            if (li == 0) atomicAdd(&rs[strip_base + nl + r], p);
        }
    }
}

// ---------------------------------------------------------------------------
// pv64: mean/msq over k=m via MFMA 32x32x16 (dual chains, H^2 in-register).
// 64c x 64n tile, 4 waves. K-step 64. XOR-swizzled LDS, DOUBLE-buffered,
// + 2-slot register prefetch (load tile t+2 while computing t, write t+1
// after the MFMA cluster so its vmcnt wait overlaps compute). One barrier
// per phase. Flat grid + XCD-locality swizzle.
// ---------------------------------------------------------------------------
__global__ __launch_bounds__(256) void pv64(const u16* __restrict__ Hb,
    const u16* __restrict__ Sb, const float* __restrict__ rs,
    const float* __restrict__ content_b, const float* __restrict__ mu,
    const float* __restrict__ isd, float* __restrict__ out_b, int strip_base)
{
    const int t = threadIdx.x;
    const int lane = t & 63, wv = t >> 6;
    const int wr = wv >> 1, wc = wv & 1;
    const int l31 = lane & 31, h = lane >> 5;

    const int xk = blockIdx.x & 7, q = blockIdx.x >> 3;
    const int c0  = (q & 7) * 64;               // CDIM/64 == 8
    const int nl0 = ((q >> 3) * 8 + xk) * 64;   // (ns/64) % 8 == 0

    __shared__ short AS[2][64][128];            // 2 x (64 rows x 256 B), swizzled

    f32x16 am = {}, aq = {};
    const int srow  = t >> 2;
    const int sbyte = (t & 3) * 16;             // 0,16,32,48
    const int so2   = sbyte >> 1;               // short offset of 16B seg
    const u16* Hrow = &Hb[(size_t)(c0  + srow) * NPIX];
    const u16* Srow = &Sb[(size_t)(nl0 + srow) * NPIX];
    const int sw = (srow & 15) << 4;
    const int wA0 = ((sbyte      ) ^ sw) >> 1;
    const int wA1 = ((sbyte +  64) ^ sw) >> 1;
    const int wS0 = ((sbyte + 128) ^ sw) >> 1;
    const int wS1 = ((sbyte + 192) ^ sw) >> 1;

    const int ra = wr*32 + l31, rb = wc*32 + l31;
    const int swa = (ra & 15) << 4, swb = (rb & 15) << 4;

    // prologue: slotA <- tile0, slotB <- tile1; LDS[0] <- slotA
    bf16x8 hA0 = *(const bf16x8*)&Hrow[so2];
    bf16x8 hA1 = *(const bf16x8*)&Hrow[so2 + 32];
    bf16x8 sA0 = *(const bf16x8*)&Srow[so2];
    bf16x8 sA1 = *(const bf16x8*)&Srow[so2 + 32];
    bf16x8 hB0 = *(const bf16x8*)&Hrow[64 + so2];
    bf16x8 hB1 = *(const bf16x8*)&Hrow[64 + so2 + 32];
    bf16x8 sB0 = *(const bf16x8*)&Srow[64 + so2];
    bf16x8 sB1 = *(const bf16x8*)&Srow[64 + so2 + 32];
    {
        short* wp = &AS[0][srow][0];
        *(bf16x8*)&wp[wA0] = hA0; *(bf16x8*)&wp[wA1] = hA1;
        *(bf16x8*)&wp[wS0] = sA0; *(bf16x8*)&wp[wS1] = sA1;
    }
    __syncthreads();

    for (int kb = 0; kb < NPIX; kb += 128) {
        // ---- phase even: compute tile kb/64 from AS[0] ----
        if (kb + 128 < NPIX) {
            hA0 = *(const bf16x8*)&Hrow[kb + 128 + so2];
            hA1 = *(const bf16x8*)&Hrow[kb + 128 + so2 + 32];
            sA0 = *(const bf16x8*)&Srow[kb + 128 + so2];
            sA1 = *(const bf16x8*)&Srow[kb + 128 + so2 + 32];
        }
        {
            const short* rpa = &AS[0][ra][0];
            const short* rpb = &AS[0][rb][0];
            #pragma unroll
            for (int ks = 0; ks < 4; ks++) {
                bf16x8 a  = *(const bf16x8*)&rpa[((ks*32 + h*16      ) ^ swa) >> 1];
                bf16x8 b  = *(const bf16x8*)&rpb[((ks*32 + h*16 + 128) ^ swb) >> 1];
                bf16x8 a2 = sq_bf16x8(a);
                am = MFMA32(a,  b, am, 0, 0, 0);
                aq = MFMA32(a2, b, aq, 0, 0, 0);
            }
        }
        {
            short* wp = &AS[1][srow][0];
            *(bf16x8*)&wp[wA0] = hB0; *(bf16x8*)&wp[wA1] = hB1;
            *(bf16x8*)&wp[wS0] = sB0; *(bf16x8*)&wp[wS1] = sB1;
        }
        __syncthreads();
        // ---- phase odd: compute tile kb/64+1 from AS[1] ----
        if (kb + 192 < NPIX) {
            hB0 = *(const bf16x8*)&Hrow[kb + 192 + so2];
            hB1 = *(const bf16x8*)&Hrow[kb + 192 + so2 + 32];
            sB0 = *(const bf16x8*)&Srow[kb + 192 + so2];
            sB1 = *(const bf16x8*)&Srow[kb + 192 + so2 + 32];
        }
        {
            const short* rpa = &AS[1][ra][0];
            const short* rpb = &AS[1][rb][0];
            #pragma unroll
            for (int ks = 0; ks < 4; ks++) {
                bf16x8 a  = *(const bf16x8*)&rpa[((ks*32 + h*16      ) ^ swa) >> 1];
                bf16x8 b  = *(const bf16x8*)&rpb[((ks*32 + h*16 + 128) ^ swb) >> 1];
                bf16x8 a2 = sq_bf16x8(a);
                am = MFMA32(a,  b, am, 0, 0, 0);
                aq = MFMA32(a2, b, aq, 0, 0, 0);
            }
        }
        if (kb + 128 < NPIX) {
            short* wp = &AS[0][srow][0];
            *(bf16x8*)&wp[wA0] = hA0; *(bf16x8*)&wp[wA1] = hA1;
            *(bf16x8*)&wp[wS0] = sA0; *(bf16x8*)&wp[wS1] = sA1;
        }
        __syncthreads();
    }

    // C layout (32x32): col = lane&31 (n), row = (reg&3) + 8*(reg>>2) + 4*h (c)
    const int n = strip_base + nl0 + wc*32 + l31;
    const float inv = 1.f / (rs[n] + EPSN);
    #pragma unroll
    for (int qd = 0; qd < 4; qd++) {
        const int cb = c0 + wr*32 + 8*qd + 4*h;
        float4 mu4 = *(const float4*)&mu[cb];
        float4 is4 = *(const float4*)&isd[cb];
        const float muA[4] = { mu4.x, mu4.y, mu4.z, mu4.w };
        const float isA[4] = { is4.x, is4.y, is4.z, is4.w };
        #pragma unroll
        for (int r2 = 0; r2 < 4; r2++) {
            const int reg = qd*4 + r2;
            float mean = am[reg] * inv;
            float msq  = aq[reg] * inv;
            float sd   = sqrtf(fmaxf(msq - mean*mean, 0.f));
            float cv   = content_b[(size_t)(cb + r2) * NPIX + n];
            out_b[(size_t)(cb + r2) * NPIX + n] = sd * (cv - muA[r2]) * isA[r2] + mean;
        }
    }
}

// ---------------------------------------------------------------------------
// content_stats: per (b,c) mean and 1/std (unbiased var, +1e-5), fp32 input
// ---------------------------------------------------------------------------
__global__ __launch_bounds__(256) void content_stats(const float* __restrict__ x,
    float* __restrict__ mu, float* __restrict__ isd)
{
    const int bc = blockIdx.x;
    const int tid = threadIdx.x;
    const float* row = x + (size_t)bc * NPIX;
    float s = 0.f, s2 = 0.f;
    for (int i = tid * 4; i < NPIX; i += 256 * 4) {
        float4 v = *(const float4*)&row[i];
        s  += v.x + v.y + v.z + v.w;
        s2 += v.x*v.x + v.y*v.y + v.z*v.z + v.w*v.w;
    }
    __shared__ float r1[256], r2[256];
    r1[tid] = s; r2[tid] = s2; __syncthreads();
    for (int st = 128; st; st >>= 1) {
        if (tid < st) { r1[tid] += r1[tid+st]; r2[tid] += r2[tid+st]; }
        __syncthreads();
    }
    if (tid == 0) {
        float m = r1[0] / NPIX;
        float var = (r2[0] - (float)NPIX * m * m) / (float)(NPIX - 1);
        mu[bc]  = m;
        isd[bc] = rsqrtf(var + 1e-5f);
    }
}

// ---------------------------------------------------------------------------
extern "C" void kernel_launch(void* const* d_in, const int* in_sizes, int n_in,
                              void* d_out, int out_size, void* d_ws, size_t ws_size,
                              hipStream_t stream)
{
    const float* content     = (const float*)d_in[0];
    const float* style       = (const float*)d_in[1];
    const float* content_key = (const float*)d_in[2];
    const float* style_key   = (const float*)d_in[3];
    const float* Wf  = (const float*)d_in[4];
    const float* bf_ = (const float*)d_in[5];
    const float* Wg  = (const float*)d_in[6];
    const float* bg  = (const float*)d_in[7];
    const float* Wh  = (const float*)d_in[8];
    const float* bh  = (const float*)d_in[9];
    float* out = (float*)d_out;

    const size_t TB = (size_t)CDIM * NPIX;   // elems per batch-tensor

    const size_t tail_bytes = ((size_t)NPIX * 3 + 2 * (size_t)B_SZ * CDIM) * 4 + 256;
    const size_t fixed = 6 * TB * 2 + tail_bytes;
    int ns = 512;
    for (int cand = NPIX; cand >= 512; cand >>= 1) {
        if (fixed + (size_t)NPIX * cand * 2 <= ws_size) { ns = cand; break; }
    }

    u16* FT  = (u16*)d_ws;                   // [NPIX][CDIM]
    u16* GT  = FT + TB;                      // [NPIX][CDIM]
    u16* Hb  = GT + TB;                      // [CDIM][NPIX]
    u16* XT0 = Hb + TB;                      // [NPIX][CDIM]
    u16* XT1 = XT0 + TB;
    u16* XT2 = XT1 + TB;
    u16* Sb  = XT2 + TB;                     // [ns][NPIX]
    float* Fn  = (float*)(Sb + (size_t)NPIX * ns);
    float* Gn  = Fn + NPIX;
    float* rsb = Gn + NPIX;
    float* mu  = rsb + NPIX;
    float* isd = mu + (size_t)B_SZ * CDIM;

    content_stats<<<B_SZ * CDIM, 256, 0, stream>>>(content, mu, isd);

    const int sg_swz = ((ns / 128) % 8 == 0) ? 1 : 0;
    const int sg_blocks = (NPIX / 128) * (ns / 128);
    const int pv_blocks = 8 * (ns / 64);

    for (int b = 0; b < B_SZ; b++) {
        const size_t bo = (size_t)b * TB;

        transpose3<<<dim3(NPIX/64, CDIM/64, 3), 256, 0, stream>>>(
                content_key, style_key, style, XT0, XT1, XT2, bo);

        conv3<<<dim3(NPIX/64, CDIM/64, 3), 256, 0, stream>>>(
                XT0, XT1, XT2, Wf, Wg, Wh, bf_, bg, bh, FT, GT, Hb);

        norm2<<<dim3(NPIX/256, 2), 256, 0, stream>>>(FT, GT, Fn, Gn, rsb);

        for (int s0 = 0; s0 < NPIX; s0 += ns) {
            s_gemm128<<<sg_blocks, 256, 0, stream>>>(FT, GT, Fn, Gn, Sb, rsb, s0, sg_swz);
            pv64<<<pv_blocks, 256, 0, stream>>>(Hb, Sb, rsb,
                    content + bo, mu + b*CDIM, isd + b*CDIM, out + bo, s0);
        }
    }
}

// Round 12
// 527.947 us; speedup vs baseline: 1.4962x; 1.0118x over previous
//
#include <hip/hip_runtime.h>
#include <hip/hip_bf16.h>
#include <math.h>

#define B_SZ 4
#define CDIM 512
#define NPIX 4096
#define EPSN 1e-5f

typedef unsigned short u16;
typedef __attribute__((ext_vector_type(8))) short bf16x8;
typedef __attribute__((ext_vector_type(4))) float f32x4;
typedef __attribute__((ext_vector_type(16))) float f32x16;

#define MFMA_BF16 __builtin_amdgcn_mfma_f32_16x16x32_bf16
#define MFMA32    __builtin_amdgcn_mfma_f32_32x32x16_bf16

static __device__ __forceinline__ float bf2f(u16 u) {
    return __uint_as_float(((unsigned)u) << 16);
}
static __device__ __forceinline__ u16 f2bf(float f) {
    unsigned u = __float_as_uint(f);
    unsigned r = (u + 0x7FFFu + ((u >> 16) & 1u)) >> 16;
    return (u16)r;
}
// packed square of a bf16x8 fragment, truncating round (bias < 2^-8 rel)
static __device__ __forceinline__ bf16x8 sq_bf16x8(bf16x8 a) {
    union { bf16x8 v; unsigned w[4]; } in, out;
    in.v = a;
    #pragma unroll
    for (int k = 0; k < 4; k++) {
        unsigned wl = in.w[k] << 16;
        unsigned wh = in.w[k] & 0xFFFF0000u;
        float sl = __uint_as_float(wl); sl *= sl;
        float sh = __uint_as_float(wh); sh *= sh;
        out.w[k] = (__float_as_uint(sh) & 0xFFFF0000u) | (__float_as_uint(sl) >> 16);
    }
    return out.v;
}

// ---------------------------------------------------------------------------
// transpose3: z selects source fp32 [CDIM][NPIX] -> XTz bf16 [NPIX][CDIM]
// ---------------------------------------------------------------------------
__global__ __launch_bounds__(256) void transpose3(const float* __restrict__ X0,
    const float* __restrict__ X1, const float* __restrict__ X2,
    u16* __restrict__ T0, u16* __restrict__ T1, u16* __restrict__ T2, size_t boff)
{
    const int z = blockIdx.z;
    const float* X = (z == 0 ? X0 : z == 1 ? X1 : X2) + boff;
    u16* XT = z == 0 ? T0 : z == 1 ? T1 : T2;

    __shared__ float T[64][65];
    const int t = threadIdx.x;
    const int n0 = blockIdx.x * 64, c0 = blockIdx.y * 64;
    #pragma unroll
    for (int p = 0; p < 4; p++) {
        int c_l = (t >> 4) + p * 16;
        int n_l = (t & 15) * 4;
        float4 v = *(const float4*)&X[(size_t)(c0 + c_l) * NPIX + n0 + n_l];
        T[c_l][n_l+0] = v.x; T[c_l][n_l+1] = v.y; T[c_l][n_l+2] = v.z; T[c_l][n_l+3] = v.w;
    }
    __syncthreads();
    #pragma unroll
    for (int p = 0; p < 4; p++) {
        int n_l = t >> 2;
        int cs  = (t & 3) * 4 + p * 16;
        ushort4 r;
        r.x = f2bf(T[cs+0][n_l]); r.y = f2bf(T[cs+1][n_l]);
        r.z = f2bf(T[cs+2][n_l]); r.w = f2bf(T[cs+3][n_l]);
        *(ushort4*)&XT[(size_t)(n0 + n_l) * CDIM + c0 + cs] = r;
    }
}

// ---------------------------------------------------------------------------
// conv3: z in {0,1,2}: D[o][n] = bias[o] + sum_c Wz[o][c]*XTz[n][c]
// z<2: store D^T to Yz=[n][CDIM] bf16 (FT/GT). z==2: store Hb=[CDIM][NPIX].
// 64x64 tile, 4 waves (2x2 of 32x32). 2-phase prefetch pipeline.
// ---------------------------------------------------------------------------
__global__ __launch_bounds__(256) void conv3(
    const u16* __restrict__ XT0, const u16* __restrict__ XT1, const u16* __restrict__ XT2,
    const float* __restrict__ W0, const float* __restrict__ W1, const float* __restrict__ W2,
    const float* __restrict__ b0, const float* __restrict__ b1, const float* __restrict__ b2,
    u16* __restrict__ Y0, u16* __restrict__ Y1, u16* __restrict__ Y2)
{
    const int z = blockIdx.z;
    const u16* XT = z == 0 ? XT0 : z == 1 ? XT1 : XT2;
    const float* W = z == 0 ? W0 : z == 1 ? W1 : W2;
    const float* bias = z == 0 ? b0 : z == 1 ? b1 : b2;

    const int t = threadIdx.x;
    const int lane = t & 63, wv = t >> 6;
    const int wr = wv >> 1, wc = wv & 1;
    const int n0 = blockIdx.x * 64;
    const int o0 = blockIdx.y * 64;
    const int g = lane >> 4, li = lane & 15;

    __shared__ short Aw[64][40];
    __shared__ short Bx[64][40];

    f32x4 acc[2][2] = {};
    const int srow = t >> 2, sseg = (t & 3) * 8;

    float4 w0 = *(const float4*)&W[(size_t)(o0 + srow) * CDIM + sseg];
    float4 w1 = *(const float4*)&W[(size_t)(o0 + srow) * CDIM + sseg + 4];
    bf16x8 bv = *(const bf16x8*)&XT[(size_t)(n0 + srow) * CDIM + sseg];

    for (int kb = 0; kb < CDIM; kb += 32) {
        bf16x8 wa;
        wa[0] = (short)f2bf(w0.x); wa[1] = (short)f2bf(w0.y);
        wa[2] = (short)f2bf(w0.z); wa[3] = (short)f2bf(w0.w);
        wa[4] = (short)f2bf(w1.x); wa[5] = (short)f2bf(w1.y);
        wa[6] = (short)f2bf(w1.z); wa[7] = (short)f2bf(w1.w);
        __syncthreads();
        *(bf16x8*)&Aw[srow][sseg] = wa;
        *(bf16x8*)&Bx[srow][sseg] = bv;
        if (kb + 32 < CDIM) {
            w0 = *(const float4*)&W[(size_t)(o0 + srow) * CDIM + kb + 32 + sseg];
            w1 = *(const float4*)&W[(size_t)(o0 + srow) * CDIM + kb + 32 + sseg + 4];
            bv = *(const bf16x8*)&XT[(size_t)(n0 + srow) * CDIM + kb + 32 + sseg];
        }
        __syncthreads();
        bf16x8 a[2], b[2];
        #pragma unroll
        for (int i = 0; i < 2; i++) a[i] = *(const bf16x8*)&Aw[wr*32 + i*16 + li][g*8];
        #pragma unroll
        for (int j = 0; j < 2; j++) b[j] = *(const bf16x8*)&Bx[wc*32 + j*16 + li][g*8];
        #pragma unroll
        for (int i = 0; i < 2; i++)
            #pragma unroll
            for (int j = 0; j < 2; j++)
                acc[i][j] = MFMA_BF16(a[i], b[j], acc[i][j], 0, 0, 0);
    }

    #pragma unroll
    for (int i = 0; i < 2; i++) {
        const int orow = o0 + wr*32 + i*16 + 4*g;
        float4 bs = *(const float4*)&bias[orow];
        #pragma unroll
        for (int j = 0; j < 2; j++) {
            const int ncol = n0 + wc*32 + j*16 + li;
            if (z < 2) {
                u16* Y = z == 0 ? Y0 : Y1;
                ushort4 r;
                r.x = f2bf(acc[i][j][0] + bs.x);
                r.y = f2bf(acc[i][j][1] + bs.y);
                r.z = f2bf(acc[i][j][2] + bs.z);
                r.w = f2bf(acc[i][j][3] + bs.w);
                *(ushort4*)&Y[(size_t)ncol * CDIM + orow] = r;
            } else {
                const float bb[4] = { bs.x, bs.y, bs.z, bs.w };
                #pragma unroll
                for (int r = 0; r < 4; r++)
                    Y2[(size_t)(orow + r) * NPIX + ncol] = f2bf(acc[i][j][r] + bb[r]);
            }
        }
    }
}

// ---------------------------------------------------------------------------
// norm2: z=0: Fn[n]=sqrt(sum FT[n][c]^2), rs[n]=0 ; z=1: Gn from GT
// ---------------------------------------------------------------------------
__global__ __launch_bounds__(256) void norm2(const u16* __restrict__ FT,
    const u16* __restrict__ GT, float* __restrict__ Fn, float* __restrict__ Gn,
    float* __restrict__ rs)
{
    const int z = blockIdx.y;
    const int n = blockIdx.x * 256 + threadIdx.x;
    const u16* row = (z ? GT : FT) + (size_t)n * CDIM;
    float s = 0.f;
    for (int c = 0; c < CDIM; c += 8) {
        bf16x8 v = *(const bf16x8*)&row[c];
        #pragma unroll
        for (int e = 0; e < 8; e++) { float f = bf2f((u16)v[e]); s += f * f; }
    }
    (z ? Gn : Fn)[n] = sqrtf(s);
    if (!z) rs[n] = 0.f;
}

// ---------------------------------------------------------------------------
// s_gemm128: S[nl][m] = bf16(relu(dot/((Fn+e)(Gn+e)) + 1)), + rowsum atomics.
// 128x128 tile, 4 waves (2x2 of 64x64), K=CDIM. LDS dbuf + 2-slot reg
// prefetch. __launch_bounds__(256,2): 256-VGPR budget so the prefetch
// slots stay live (at the default 64-VGPR cap the compiler sinks the loads
// and the pipeline collapses to serial-latency phases).
// ---------------------------------------------------------------------------
__global__ __launch_bounds__(256, 2) void s_gemm128(const u16* __restrict__ FT,
    const u16* __restrict__ GT, const float* __restrict__ Fn, const float* __restrict__ Gn,
    u16* __restrict__ S, float* __restrict__ rs, int strip_base, int swz)
{
    const int t = threadIdx.x;
    const int lane = t & 63, wv = t >> 6;
    const int wr = wv >> 1, wc = wv & 1;

    int mm, nn;
    if (swz) {            // (ns/128) % 8 == 0
        const int xk = blockIdx.x & 7, q = blockIdx.x >> 3;
        mm = q & 31;                      // NPIX/128 == 32
        nn = (q >> 5) * 8 + xk;
    } else {
        mm = blockIdx.x & 31;
        nn = blockIdx.x >> 5;
    }
    const int m0  = mm * 128;
    const int nl0 = nn * 128;
    const int ng0 = strip_base + nl0;
    const int g = lane >> 4, li = lane & 15;

    __shared__ short As[2][128][40];
    __shared__ short Bs[2][128][40];

    f32x4 acc[4][4] = {};
    const int srow = t >> 2, sseg = (t & 3) * 8;
    const u16* Fr0 = &FT[(size_t)(ng0 + srow     ) * CDIM];
    const u16* Fr1 = &FT[(size_t)(ng0 + srow + 64) * CDIM];
    const u16* Gr0 = &GT[(size_t)(m0  + srow     ) * CDIM];
    const u16* Gr1 = &GT[(size_t)(m0  + srow + 64) * CDIM];

    bf16x8 fA0 = *(const bf16x8*)&Fr0[sseg];
    bf16x8 fA1 = *(const bf16x8*)&Fr1[sseg];
    bf16x8 gA0 = *(const bf16x8*)&Gr0[sseg];
    bf16x8 gA1 = *(const bf16x8*)&Gr1[sseg];
    bf16x8 fB0 = *(const bf16x8*)&Fr0[32 + sseg];
    bf16x8 fB1 = *(const bf16x8*)&Fr1[32 + sseg];
    bf16x8 gB0 = *(const bf16x8*)&Gr0[32 + sseg];
    bf16x8 gB1 = *(const bf16x8*)&Gr1[32 + sseg];
    *(bf16x8*)&As[0][srow     ][sseg] = fA0;
    *(bf16x8*)&As[0][srow + 64][sseg] = fA1;
    *(bf16x8*)&Bs[0][srow     ][sseg] = gA0;
    *(bf16x8*)&Bs[0][srow + 64][sseg] = gA1;
    __syncthreads();

    for (int kb = 0; kb < CDIM; kb += 64) {
        if (kb + 64 < CDIM) {
            fA0 = *(const bf16x8*)&Fr0[kb + 64 + sseg];
            fA1 = *(const bf16x8*)&Fr1[kb + 64 + sseg];
            gA0 = *(const bf16x8*)&Gr0[kb + 64 + sseg];
            gA1 = *(const bf16x8*)&Gr1[kb + 64 + sseg];
        }
        {
            bf16x8 a[4], b[4];
            #pragma unroll
            for (int i = 0; i < 4; i++) a[i] = *(const bf16x8*)&As[0][wr*64 + i*16 + li][g*8];
            #pragma unroll
            for (int j = 0; j < 4; j++) b[j] = *(const bf16x8*)&Bs[0][wc*64 + j*16 + li][g*8];
            #pragma unroll
            for (int i = 0; i < 4; i++)
                #pragma unroll
                for (int j = 0; j < 4; j++)
                    acc[i][j] = MFMA_BF16(a[i], b[j], acc[i][j], 0, 0, 0);
        }
        *(bf16x8*)&As[1][srow     ][sseg] = fB0;
        *(bf16x8*)&As[1][srow + 64][sseg] = fB1;
        *(bf16x8*)&Bs[1][srow     ][sseg] = gB0;
        *(bf16x8*)&Bs[1][srow + 64][sseg] = gB1;
        __syncthreads();
        if (kb + 96 < CDIM) {
            fB0 = *(const bf16x8*)&Fr0[kb + 96 + sseg];
            fB1 = *(const bf16x8*)&Fr1[kb + 96 + sseg];
            gB0 = *(const bf16x8*)&Gr0[kb + 96 + sseg];
            gB1 = *(const bf16x8*)&Gr1[kb + 96 + sseg];
        }
        {
            bf16x8 a[4], b[4];
            #pragma unroll
            for (int i = 0; i < 4; i++) a[i] = *(const bf16x8*)&As[1][wr*64 + i*16 + li][g*8];
            #pragma unroll
            for (int j = 0; j < 4; j++) b[j] = *(const bf16x8*)&Bs[1][wc*64 + j*16 + li][g*8];
            #pragma unroll
            for (int i = 0; i < 4; i++)
                #pragma unroll
                for (int j = 0; j < 4; j++)
                    acc[i][j] = MFMA_BF16(a[i], b[j], acc[i][j], 0, 0, 0);
        }
        if (kb + 64 < CDIM) {
            *(bf16x8*)&As[0][srow     ][sseg] = fA0;
            *(bf16x8*)&As[0][srow + 64][sseg] = fA1;
            *(bf16x8*)&Bs[0][srow     ][sseg] = gA0;
            *(bf16x8*)&Bs[0][srow + 64][sseg] = gA1;
        }
        __syncthreads();
    }

    float gi[4];
    #pragma unroll
    for (int j = 0; j < 4; j++) gi[j] = 1.f / (Gn[m0 + wc*64 + j*16 + li] + EPSN);
    #pragma unroll
    for (int i = 0; i < 4; i++) {
        const int nl = nl0 + wr*64 + i*16 + 4*g;
        float4 fn4 = *(const float4*)&Fn[strip_base + nl];
        const float fi4[4] = { 1.f/(fn4.x + EPSN), 1.f/(fn4.y + EPSN),
                               1.f/(fn4.z + EPSN), 1.f/(fn4.w + EPSN) };
        float ps[4] = {0.f, 0.f, 0.f, 0.f};
        #pragma unroll
        for (int j = 0; j < 4; j++) {
            const int m = m0 + wc*64 + j*16 + li;
            #pragma unroll
            for (int r = 0; r < 4; r++) {
                float v = fmaxf(acc[i][j][r] * fi4[r] * gi[j] + 1.f, 0.f);
                u16 hv = f2bf(v);
                S[(size_t)(nl + r) * NPIX + m] = hv;
                ps[r] += bf2f(hv);
            }
        }
        #pragma unroll
        for (int r = 0; r < 4; r++) {
            float p = ps[r];
            p += __shfl_xor(p, 1);
            p += __shfl_xor(p, 2);
            p += __shfl_xor(p, 4);
            p += __shfl_xor(p, 8);
            if (li == 0) atomicAdd(&rs[strip_base + nl + r], p);
        }
    }
}

// ---------------------------------------------------------------------------
// pv64: mean/msq over k=m via MFMA 32x32x16 (dual chains, H^2 in-register).
// 64c x 64n tile, 4 waves. K-step 64. XOR-swizzled LDS, double-buffered,
// 2-slot register prefetch. __launch_bounds__(256,2): grid gives only
// 2 blocks/CU anyway, so the default 64-VGPR cap bought nothing and cost
// the prefetch (round-11 VGPR_Count=64 tell). Flat grid + XCD swizzle.
// ---------------------------------------------------------------------------
__global__ __launch_bounds__(256, 2) void pv64(const u16* __restrict__ Hb,
    const u16* __restrict__ Sb, const float* __restrict__ rs,
    const float* __restrict__ content_b, const float* __restrict__ mu,
    const float* __restrict__ isd, float* __restrict__ out_b, int strip_base)
{
    const int t = threadIdx.x;
    const int lane = t & 63, wv = t >> 6;
    const int wr = wv >> 1, wc = wv & 1;
    const int l31 = lane & 31, h = lane >> 5;

    const int xk = blockIdx.x & 7, q = blockIdx.x >> 3;
    const int c0  = (q & 7) * 64;               // CDIM/64 == 8
    const int nl0 = ((q >> 3) * 8 + xk) * 64;   // (ns/64) % 8 == 0

    __shared__ short AS[2][64][128];            // 2 x (64 rows x 256 B), swizzled

    f32x16 am = {}, aq = {};
    const int srow  = t >> 2;
    const int sbyte = (t & 3) * 16;             // 0,16,32,48
    const int so2   = sbyte >> 1;               // short offset of 16B seg
    const u16* Hrow = &Hb[(size_t)(c0  + srow) * NPIX];
    const u16* Srow = &Sb[(size_t)(nl0 + srow) * NPIX];
    const int sw = (srow & 15) << 4;
    const int wA0 = ((sbyte      ) ^ sw) >> 1;
    const int wA1 = ((sbyte +  64) ^ sw) >> 1;
    const int wS0 = ((sbyte + 128) ^ sw) >> 1;
    const int wS1 = ((sbyte + 192) ^ sw) >> 1;

    const int ra = wr*32 + l31, rb = wc*32 + l31;
    const int swa = (ra & 15) << 4, swb = (rb & 15) << 4;

    bf16x8 hA0 = *(const bf16x8*)&Hrow[so2];
    bf16x8 hA1 = *(const bf16x8*)&Hrow[so2 + 32];
    bf16x8 sA0 = *(const bf16x8*)&Srow[so2];
    bf16x8 sA1 = *(const bf16x8*)&Srow[so2 + 32];
    bf16x8 hB0 = *(const bf16x8*)&Hrow[64 + so2];
    bf16x8 hB1 = *(const bf16x8*)&Hrow[64 + so2 + 32];
    bf16x8 sB0 = *(const bf16x8*)&Srow[64 + so2];
    bf16x8 sB1 = *(const bf16x8*)&Srow[64 + so2 + 32];
    {
        short* wp = &AS[0][srow][0];
        *(bf16x8*)&wp[wA0] = hA0; *(bf16x8*)&wp[wA1] = hA1;
        *(bf16x8*)&wp[wS0] = sA0; *(bf16x8*)&wp[wS1] = sA1;
    }
    __syncthreads();

    for (int kb = 0; kb < NPIX; kb += 128) {
        // ---- phase even: compute tile kb/64 from AS[0] ----
        if (kb + 128 < NPIX) {
            hA0 = *(const bf16x8*)&Hrow[kb + 128 + so2];
            hA1 = *(const bf16x8*)&Hrow[kb + 128 + so2 + 32];
            sA0 = *(const bf16x8*)&Srow[kb + 128 + so2];
            sA1 = *(const bf16x8*)&Srow[kb + 128 + so2 + 32];
        }
        {
            const short* rpa = &AS[0][ra][0];
            const short* rpb = &AS[0][rb][0];
            #pragma unroll
            for (int ks = 0; ks < 4; ks++) {
                bf16x8 a  = *(const bf16x8*)&rpa[((ks*32 + h*16      ) ^ swa) >> 1];
                bf16x8 b  = *(const bf16x8*)&rpb[((ks*32 + h*16 + 128) ^ swb) >> 1];
                bf16x8 a2 = sq_bf16x8(a);
                am = MFMA32(a,  b, am, 0, 0, 0);
                aq = MFMA32(a2, b, aq, 0, 0, 0);
            }
        }
        {
            short* wp = &AS[1][srow][0];
            *(bf16x8*)&wp[wA0] = hB0; *(bf16x8*)&wp[wA1] = hB1;
            *(bf16x8*)&wp[wS0] = sB0; *(bf16x8*)&wp[wS1] = sB1;
        }
        __syncthreads();
        // ---- phase odd: compute tile kb/64+1 from AS[1] ----
        if (kb + 192 < NPIX) {
            hB0 = *(const bf16x8*)&Hrow[kb + 192 + so2];
            hB1 = *(const bf16x8*)&Hrow[kb + 192 + so2 + 32];
            sB0 = *(const bf16x8*)&Srow[kb + 192 + so2];
            sB1 = *(const bf16x8*)&Srow[kb + 192 + so2 + 32];
        }
        {
            const short* rpa = &AS[1][ra][0];
            const short* rpb = &AS[1][rb][0];
            #pragma unroll
            for (int ks = 0; ks < 4; ks++) {
                bf16x8 a  = *(const bf16x8*)&rpa[((ks*32 + h*16      ) ^ swa) >> 1];
                bf16x8 b  = *(const bf16x8*)&rpb[((ks*32 + h*16 + 128) ^ swb) >> 1];
                bf16x8 a2 = sq_bf16x8(a);
                am = MFMA32(a,  b, am, 0, 0, 0);
                aq = MFMA32(a2, b, aq, 0, 0, 0);
            }
        }
        if (kb + 128 < NPIX) {
            short* wp = &AS[0][srow][0];
            *(bf16x8*)&wp[wA0] = hA0; *(bf16x8*)&wp[wA1] = hA1;
            *(bf16x8*)&wp[wS0] = sA0; *(bf16x8*)&wp[wS1] = sA1;
        }
        __syncthreads();
    }

    // C layout (32x32): col = lane&31 (n), row = (reg&3) + 8*(reg>>2) + 4*h (c)
    const int n = strip_base + nl0 + wc*32 + l31;
    const float inv = 1.f / (rs[n] + EPSN);
    #pragma unroll
    for (int qd = 0; qd < 4; qd++) {
        const int cb = c0 + wr*32 + 8*qd + 4*h;
        float4 mu4 = *(const float4*)&mu[cb];
        float4 is4 = *(const float4*)&isd[cb];
        const float muA[4] = { mu4.x, mu4.y, mu4.z, mu4.w };
        const float isA[4] = { is4.x, is4.y, is4.z, is4.w };
        #pragma unroll
        for (int r2 = 0; r2 < 4; r2++) {
            const int reg = qd*4 + r2;
            float mean = am[reg] * inv;
            float msq  = aq[reg] * inv;
            float sd   = sqrtf(fmaxf(msq - mean*mean, 0.f));
            float cv   = content_b[(size_t)(cb + r2) * NPIX + n];
            out_b[(size_t)(cb + r2) * NPIX + n] = sd * (cv - muA[r2]) * isA[r2] + mean;
        }
    }
}

// ---------------------------------------------------------------------------
// content_stats: per (b,c) mean and 1/std (unbiased var, +1e-5), fp32 input
// ---------------------------------------------------------------------------
__global__ __launch_bounds__(256) void content_stats(const float* __restrict__ x,
    float* __restrict__ mu, float* __restrict__ isd)
{
    const int bc = blockIdx.x;
    const int tid = threadIdx.x;
    const float* row = x + (size_t)bc * NPIX;
    float s = 0.f, s2 = 0.f;
    for (int i = tid * 4; i < NPIX; i += 256 * 4) {
        float4 v = *(const float4*)&row[i];
        s  += v.x + v.y + v.z + v.w;
        s2 += v.x*v.x + v.y*v.y + v.z*v.z + v.w*v.w;
    }
    __shared__ float r1[256], r2[256];
    r1[tid] = s; r2[tid] = s2; __syncthreads();
    for (int st = 128; st; st >>= 1) {
        if (tid < st) { r1[tid] += r1[tid+st]; r2[tid] += r2[tid+st]; }
        __syncthreads();
    }
    if (tid == 0) {
        float m = r1[0] / NPIX;
        float var = (r2[0] - (float)NPIX * m * m) / (float)(NPIX - 1);
        mu[bc]  = m;
        isd[bc] = rsqrtf(var + 1e-5f);
    }
}

// ---------------------------------------------------------------------------
extern "C" void kernel_launch(void* const* d_in, const int* in_sizes, int n_in,
                              void* d_out, int out_size, void* d_ws, size_t ws_size,
                              hipStream_t stream)
{
    const float* content     = (const float*)d_in[0];
    const float* style       = (const float*)d_in[1];
    const float* content_key = (const float*)d_in[2];
    const float* style_key   = (const float*)d_in[3];
    const float* Wf  = (const float*)d_in[4];
    const float* bf_ = (const float*)d_in[5];
    const float* Wg  = (const float*)d_in[6];
    const float* bg  = (const float*)d_in[7];
    const float* Wh  = (const float*)d_in[8];
    const float* bh  = (const float*)d_in[9];
    float* out = (float*)d_out;

    const size_t TB = (size_t)CDIM * NPIX;   // elems per batch-tensor

    const size_t tail_bytes = ((size_t)NPIX * 3 + 2 * (size_t)B_SZ * CDIM) * 4 + 256;
    const size_t fixed = 6 * TB * 2 + tail_bytes;
    int ns = 512;
    for (int cand = NPIX; cand >= 512; cand >>= 1) {
        if (fixed + (size_t)NPIX * cand * 2 <= ws_size) { ns = cand; break; }
    }

    u16* FT  = (u16*)d_ws;                   // [NPIX][CDIM]
    u16* GT  = FT + TB;                      // [NPIX][CDIM]
    u16* Hb  = GT + TB;                      // [CDIM][NPIX]
    u16* XT0 = Hb + TB;                      // [NPIX][CDIM]
    u16* XT1 = XT0 + TB;
    u16* XT2 = XT1 + TB;
    u16* Sb  = XT2 + TB;                     // [ns][NPIX]
    float* Fn  = (float*)(Sb + (size_t)NPIX * ns);
    float* Gn  = Fn + NPIX;
    float* rsb = Gn + NPIX;
    float* mu  = rsb + NPIX;
    float* isd = mu + (size_t)B_SZ * CDIM;

    content_stats<<<B_SZ * CDIM, 256, 0, stream>>>(content, mu, isd);

    const int sg_swz = ((ns / 128) % 8 == 0) ? 1 : 0;
    const int sg_blocks = (NPIX / 128) * (ns / 128);
    const int pv_blocks = 8 * (ns / 64);

    for (int b = 0; b < B_SZ; b++) {
        const size_t bo = (size_t)b * TB;

        transpose3<<<dim3(NPIX/64, CDIM/64, 3), 256, 0, stream>>>(
                content_key, style_key, style, XT0, XT1, XT2, bo);

        conv3<<<dim3(NPIX/64, CDIM/64, 3), 256, 0, stream>>>(
                XT0, XT1, XT2, Wf, Wg, Wh, bf_, bg, bh, FT, GT, Hb);

        norm2<<<dim3(NPIX/256, 2), 256, 0, stream>>>(FT, GT, Fn, Gn, rsb);

        for (int s0 = 0; s0 < NPIX; s0 += ns) {
            s_gemm128<<<sg_blocks, 256, 0, stream>>>(FT, GT, Fn, Gn, Sb, rsb, s0, sg_swz);
            pv64<<<pv_blocks, 256, 0, stream>>>(Hb, Sb, rsb,
                    content + bo, mu + b*CDIM, isd + b*CDIM, out + bo, s0);
        }
    }
}